// Round 5
// baseline (1143.129 us; speedup 1.0000x reference)
//
#include <hip/hip_runtime.h>
#include <hip/hip_bf16.h>
#include <cstdint>
#include <cstddef>

// Problem constants (match reference)
#define BB 16
#define SS 384
#define GG 384
#define NN 768          // S + G
#define DD 128
#define EC 100
#define TT 21
#define NHEADS 4
#define BN (BB*NN)      // 12288
#define BS (BB*SS)      // 6144

typedef float v2f __attribute__((ext_vector_type(2)));

__device__ __forceinline__ float sigf(float x) { return 1.0f / (1.0f + __expf(-x)); }
__device__ __forceinline__ float tanh_fast(float x) {
    // 1 - 2/(exp(2x)+1); exp overflow -> inf -> 1, underflow -> 0 -> -1
    return 1.0f - 2.0f / (__expf(2.0f * x) + 1.0f);
}
__device__ __forceinline__ float wred_max(float v) {
    #pragma unroll
    for (int o = 32; o > 0; o >>= 1) v = fmaxf(v, __shfl_xor(v, o));
    return v;
}
__device__ __forceinline__ float wred_sum(float v) {
    #pragma unroll
    for (int o = 32; o > 0; o >>= 1) v += __shfl_xor(v, o);
    return v;
}
__device__ __forceinline__ float rlane(float v, int l) {
    return __uint_as_float(__builtin_amdgcn_readlane(__float_as_uint(v), l));
}

// ---------------------------------------------------------------------------
// xw = emb @ w_ih^T + b for both directions.  Tiled GEMM with char gather.
// grid (96 row-tiles, 8): blockIdx.y -> dir(2) x gate-tile(4).  64x64 tiles.
// ---------------------------------------------------------------------------
__global__ __launch_bounds__(256) void k_xw(
    const int* __restrict__ batch_char, const float* __restrict__ char_table,
    const float* __restrict__ w_ih_f, const float* __restrict__ b_f,
    const float* __restrict__ w_ih_b, const float* __restrict__ b_b,
    float* __restrict__ xw_f, float* __restrict__ xw_b)
{
    __shared__ float At[EC * 68];   // [e][row]
    __shared__ float Bt[EC * 68];   // [e][gate]
    __shared__ int   chs[64];
    const int tid = threadIdx.x;
    const int rt  = blockIdx.x;             // row tile (64 rows of B*S)
    const int ot  = blockIdx.y;             // dir*4 + gate tile
    const int dir = ot >> 2, gt = ot & 3;
    const float* wih  = dir ? w_ih_b : w_ih_f;
    const float* bias = dir ? b_b    : b_f;
    float*       out  = dir ? xw_b   : xw_f;

    if (tid < 64) chs[tid] = batch_char[rt * 64 + tid];
    __syncthreads();
    for (int idx = tid; idx < 64 * EC; idx += 256) {
        int r = idx / EC, e = idx - r * EC;
        At[e * 68 + r] = char_table[(size_t)chs[r] * EC + e];
        Bt[e * 68 + r] = wih[(size_t)(gt * 64 + r) * EC + e];
    }
    __syncthreads();

    const int ty = tid >> 4, tx = tid & 15;
    const int r0 = ty * 4, c0 = tx * 4;
    float acc[4][4] = {};
    #pragma unroll 4
    for (int e = 0; e < EC; ++e) {
        float4 a = *(const float4*)&At[e * 68 + r0];
        float4 bv = *(const float4*)&Bt[e * 68 + c0];
        float av[4] = {a.x, a.y, a.z, a.w};
        float bb[4] = {bv.x, bv.y, bv.z, bv.w};
        #pragma unroll
        for (int i = 0; i < 4; ++i)
            #pragma unroll
            for (int j = 0; j < 4; ++j) acc[i][j] = fmaf(av[i], bb[j], acc[i][j]);
    }
    #pragma unroll
    for (int i = 0; i < 4; ++i) {
        int row = rt * 64 + r0 + i;
        int gc  = gt * 64 + c0;
        float4 o;
        o.x = acc[i][0] + bias[gc + 0];
        o.y = acc[i][1] + bias[gc + 1];
        o.z = acc[i][2] + bias[gc + 2];
        o.w = acc[i][3] + bias[gc + 3];
        *(float4*)&out[(size_t)row * 256 + gc] = o;
    }
}

// ---------------------------------------------------------------------------
// gaz embedding gather into gat_in rows [S, N)
// ---------------------------------------------------------------------------
__global__ __launch_bounds__(256) void k_gaz(
    const int* __restrict__ gaz_list, const float* __restrict__ gaz_table,
    float* __restrict__ gat_in)
{
    int idx = blockIdx.x * 256 + threadIdx.x;      // B*G*128 total
    int d = idx & 127;
    int rest = idx >> 7;
    int g = rest % GG;
    int b = rest / GG;
    float v = gaz_table[(size_t)gaz_list[b * GG + g] * DD + d];
    gat_in[((size_t)b * NN + SS + g) * DD + d] = v;
}

// ---------------------------------------------------------------------------
// BiLSTM scan.  grid 32 = (batch, dir).  ONE wave per block.
// R1 retry with the identified failure fixed.  Lane u owns unit u: h, c and
// all 4 gate rows of w_hh (256 VGPRs of weights).  R1's regalloc sank the
// weight loads back into the loop (VGPR_Count=144 -> ~1875 cyc/step of L2
// reload latency on the critical path).  Fix: pin every weight register
// with an opaque asm barrier after the one-time load -- the values become
// asm outputs, so rematerialization from memory is impossible and the
// allocator must keep ~290 VGPRs live (cap 512 at launch_bounds(64,1)).
// The 4-round-measured ~1300-cycle/step floor of ALL barrier-based
// multi-wave variants (R0/R2/R3/R4) does not apply: this kernel has NO
// barrier, NO LDS -- so the per-step xw prefetch and h store overlap the
// ~500-cycle readlane+pk_fma block freely (no vmcnt(0) drain anywhere).
// ---------------------------------------------------------------------------
__global__ __launch_bounds__(64, 1) void k_lstm(
    const float* __restrict__ xw_f, const float* __restrict__ xw_b,
    const float* __restrict__ w_hh_f, const float* __restrict__ w_hh_b,
    float* __restrict__ gat_in)
{
    const int lane = threadIdx.x;
    const int b = blockIdx.x >> 1, dir = blockIdx.x & 1;
    const float* xw  = (dir ? xw_b : xw_f) + (size_t)b * SS * 256;
    const float* whh = dir ? w_hh_b : w_hh_f;

    // Per-lane weights: w2[g][j] = { whh[(g*64+lane)*64 + 2j], ... + 2j+1 }
    // 4 gates x 32 v2f = 256 VGPRs, all indices compile-time after unroll.
    v2f w2[4][32];
    #pragma unroll
    for (int g = 0; g < 4; ++g) {
        const float4* r4 = (const float4*)(whh + (size_t)(g * 64 + lane) * 64);
        #pragma unroll
        for (int q = 0; q < 16; ++q) {
            float4 v = r4[q];
            w2[g][2 * q]     = v2f{v.x, v.y};
            w2[g][2 * q + 1] = v2f{v.z, v.w};
        }
    }
    // Pin: values become opaque asm outputs -> no remat, must stay in VGPRs.
    #pragma unroll
    for (int g = 0; g < 4; ++g)
        #pragma unroll
        for (int j = 0; j < 32; ++j)
            asm volatile("" : "+v"(w2[g][j]));

    float h = 0.f, c = 0.f;
    const int t0 = dir ? (SS - 1) : 0;
    float x0 = xw[t0 * 256 +   0 + lane];
    float x1 = xw[t0 * 256 +  64 + lane];
    float x2 = xw[t0 * 256 + 128 + lane];
    float x3 = xw[t0 * 256 + 192 + lane];
    float* outp = gat_in + ((size_t)b * NN) * DD + dir * 64 + lane;

    for (int tt = 0; tt < SS; ++tt) {
        const int t = dir ? (SS - 1 - tt) : tt;
        const int tn = dir ? (t - 1) : (t + 1);
        // Issue next-step prefetch first: it drains under the FMA block
        // (no barrier anywhere to force vmcnt(0)).
        float nx0 = 0.f, nx1 = 0.f, nx2 = 0.f, nx3 = 0.f;
        if (tt + 1 < SS) {
            nx0 = xw[tn * 256 +   0 + lane];
            nx1 = xw[tn * 256 +  64 + lane];
            nx2 = xw[tn * 256 + 128 + lane];
            nx3 = xw[tn * 256 + 192 + lane];
        }
        v2f a0 = v2f{x0, 0.f}, a1 = v2f{x1, 0.f};
        v2f a2 = v2f{x2, 0.f}, a3 = v2f{x3, 0.f};
        #pragma unroll
        for (int j = 0; j < 32; ++j) {
            v2f hp = v2f{rlane(h, 2 * j), rlane(h, 2 * j + 1)};
            a0 = __builtin_elementwise_fma(hp, w2[0][j], a0);
            a1 = __builtin_elementwise_fma(hp, w2[1][j], a1);
            a2 = __builtin_elementwise_fma(hp, w2[2][j], a2);
            a3 = __builtin_elementwise_fma(hp, w2[3][j], a3);
        }
        float gi = a0.x + a0.y, gf = a1.x + a1.y;
        float gg = a2.x + a2.y, go = a3.x + a3.y;
        float nc = sigf(gf) * c + sigf(gi) * tanh_fast(gg);
        h = sigf(go) * tanh_fast(nc);
        c = nc;
        outp[(size_t)t * DD] = h;
        x0 = nx0; x1 = nx1; x2 = nx2; x3 = nx3;
    }
}

// ---------------------------------------------------------------------------
// GAT layer-1 projection: h1 = gat_in @ Wh[k][hd] (+ per-row f1/f2 dots).
// grid (192 row-tiles, 4 heads).  64x64 tile, K=128 in 2 phases of 64.
// ---------------------------------------------------------------------------
__global__ __launch_bounds__(256) void k_p1(
    const float* __restrict__ gat_in, const float* __restrict__ gat_Wh,
    const float* __restrict__ gat_ah, int k,
    float* __restrict__ h1, float* __restrict__ f1g, float* __restrict__ f2g)
{
    __shared__ float At[64 * 68];
    __shared__ float Bt[64 * 68];
    __shared__ float sf1[64], sf2[64];
    const int tid = threadIdx.x;
    const int rt = blockIdx.x, hd = blockIdx.y;
    if (tid < 64) { sf1[tid] = 0.f; sf2[tid] = 0.f; }
    const float* W = gat_Wh + ((size_t)(k * NHEADS + hd)) * DD * 64;
    const int ty = tid >> 4, tx = tid & 15;
    const int r0 = ty * 4, c0 = tx * 4;
    float acc[4][4] = {};
    for (int ph = 0; ph < 2; ++ph) {
        __syncthreads();
        for (int idx = tid; idx < 64 * 64; idx += 256) {
            int r = idx >> 6, e = idx & 63;
            At[e * 68 + r] = gat_in[((size_t)(rt * 64 + r)) * DD + ph * 64 + e];
            Bt[e * 68 + r] = W[(size_t)(ph * 64 + e) * 64 + r];
        }
        __syncthreads();
        #pragma unroll 4
        for (int e = 0; e < 64; ++e) {
            float4 a = *(const float4*)&At[e * 68 + r0];
            float4 bv = *(const float4*)&Bt[e * 68 + c0];
            float av[4] = {a.x, a.y, a.z, a.w};
            float bb[4] = {bv.x, bv.y, bv.z, bv.w};
            #pragma unroll
            for (int i = 0; i < 4; ++i)
                #pragma unroll
                for (int j = 0; j < 4; ++j) acc[i][j] = fmaf(av[i], bb[j], acc[i][j]);
        }
    }
    const float* ah = gat_ah + (size_t)(k * NHEADS + hd) * 128;
    float a1[4], a2[4];
    #pragma unroll
    for (int j = 0; j < 4; ++j) { a1[j] = ah[c0 + j]; a2[j] = ah[64 + c0 + j]; }
    #pragma unroll
    for (int i = 0; i < 4; ++i) {
        int n = rt * 64 + r0 + i;
        float4 o = make_float4(acc[i][0], acc[i][1], acc[i][2], acc[i][3]);
        *(float4*)&h1[((size_t)n * NHEADS + hd) * 64 + c0] = o;
        float p1 = acc[i][0] * a1[0] + acc[i][1] * a1[1] + acc[i][2] * a1[2] + acc[i][3] * a1[3];
        float p2 = acc[i][0] * a2[0] + acc[i][1] * a2[1] + acc[i][2] * a2[2] + acc[i][3] * a2[3];
        atomicAdd(&sf1[r0 + i], p1);
        atomicAdd(&sf2[r0 + i], p2);
    }
    __syncthreads();
    if (tid < 64) {
        f1g[hd * BN + rt * 64 + tid] = sf1[tid];
        f2g[hd * BN + rt * 64 + tid] = sf2[tid];
    }
}

// ---------------------------------------------------------------------------
// GAT layer-1 attention (sparse).  One block per row n=(b,i); wave = head.
// Ballot-based neighbor compaction (no LDS atomics); 4-acc gather.
// Also emits bit-packed adjacency for layer 2.
// ---------------------------------------------------------------------------
__global__ __launch_bounds__(256) void k_attn1(
    const int* __restrict__ adj, const float* __restrict__ h1,
    const float* __restrict__ f1g, const float* __restrict__ f2g,
    float* __restrict__ out1, unsigned long long* __restrict__ packed)
{
    __shared__ int   nbr[NN];
    __shared__ float ep[NHEADS][NN];
    __shared__ unsigned long long wm[12];
    __shared__ int cntS;
    const int tid = threadIdx.x, wave = tid >> 6, lane = tid & 63;
    const int n = blockIdx.x;
    const int b = n / NN;
    #pragma unroll
    for (int it = 0; it < 3; ++it) {
        int j = it * 256 + tid;
        int a = adj[(size_t)n * NN + j];
        unsigned long long m = __ballot(a > 0);
        if (lane == 0) { wm[it * 4 + wave] = m; packed[(size_t)n * 12 + it * 4 + wave] = m; }
    }
    __syncthreads();
    if (wave == 0) {
        unsigned long long m = (lane < 12) ? wm[lane] : 0ULL;
        int pc = __popcll(m);
        int inc = pc;
        #pragma unroll
        for (int d = 1; d < 16; d <<= 1) { int t = __shfl_up(inc, d); if (lane >= d) inc += t; }
        int C = __shfl(inc, 11);
        if (lane == 0) cntS = C;
        int off = inc - pc;
        while (m) {
            int bit = __builtin_ctzll(m);
            nbr[off++] = lane * 64 + bit;
            m &= m - 1;
        }
    }
    __syncthreads();
    const int C = cntS;
    const int hd = wave;
    const float f1 = f1g[hd * BN + n];
    const float* f2p = f2g + hd * BN + b * NN;
    float mx = -3.0e38f;
    for (int t = lane; t < C; t += 64) {
        float e = f1 + f2p[nbr[t]];
        e = (e >= 0.f) ? e : 0.2f * e;
        ep[hd][t] = e;
        mx = fmaxf(mx, e);
    }
    mx = wred_max(mx);
    float sum = 0.f;
    for (int t = lane; t < C; t += 64) {
        float p = __expf(ep[hd][t] - mx);
        ep[hd][t] = p;
        sum += p;
    }
    sum = wred_sum(sum);
    const float* hb = h1 + (size_t)b * NN * (NHEADS * 64) + hd * 64 + lane;
    float ac0 = 0.f, ac1 = 0.f, ac2 = 0.f, ac3 = 0.f;
    int t = 0;
    for (; t + 3 < C; t += 4) {
        int j0 = nbr[t], j1 = nbr[t + 1], j2 = nbr[t + 2], j3 = nbr[t + 3];
        float p0 = ep[hd][t], p1 = ep[hd][t + 1], p2 = ep[hd][t + 2], p3 = ep[hd][t + 3];
        ac0 = fmaf(p0, hb[(size_t)j0 * 256], ac0);
        ac1 = fmaf(p1, hb[(size_t)j1 * 256], ac1);
        ac2 = fmaf(p2, hb[(size_t)j2 * 256], ac2);
        ac3 = fmaf(p3, hb[(size_t)j3 * 256], ac3);
    }
    for (; t < C; ++t) ac0 = fmaf(ep[hd][t], hb[(size_t)nbr[t] * 256], ac0);
    float r = ((ac0 + ac1) + (ac2 + ac3)) / sum;
    r = (r > 0.f) ? r : expm1f(r);
    out1[(size_t)n * 256 + hd * 64 + lane] = r;
}

// ---------------------------------------------------------------------------
// Output-layer projection: h2 = out1 @ Wo[k]  (+ f1o/f2o dots).  12 rows/block.
// ---------------------------------------------------------------------------
__global__ __launch_bounds__(256) void k_p2(
    const float* __restrict__ out1, const float* __restrict__ gat_Wo,
    const float* __restrict__ gat_ao, int k,
    float* __restrict__ h2, float* __restrict__ f1o, float* __restrict__ f2o)
{
    __shared__ float ld[12 * 256];
    __shared__ float lf1[12], lf2[12];
    const int tid = threadIdx.x;
    const int blk = blockIdx.x;
    if (tid < 12) { lf1[tid] = 0.f; lf2[tid] = 0.f; }
    for (int idx = tid; idx < 12 * 256; idx += 256)
        ld[idx] = out1[(size_t)blk * 12 * 256 + idx];
    __syncthreads();
    if (tid < 252) {
        const int r = tid / TT, c = tid - r * TT;
        const float* Wo = gat_Wo + (size_t)k * 256 * TT;
        const float4* row4 = (const float4*)&ld[r * 256];
        float acc = 0.f;
        #pragma unroll 8
        for (int q4 = 0; q4 < 64; ++q4) {
            float4 v = row4[q4];
            int q = q4 * 4;
            acc = fmaf(v.x, Wo[(q + 0) * TT + c], acc);
            acc = fmaf(v.y, Wo[(q + 1) * TT + c], acc);
            acc = fmaf(v.z, Wo[(q + 2) * TT + c], acc);
            acc = fmaf(v.w, Wo[(q + 3) * TT + c], acc);
        }
        const int n = blk * 12 + r;
        h2[(size_t)n * TT + c] = acc;
        const float* ao = gat_ao + k * 2 * TT;
        atomicAdd(&lf1[r], acc * ao[c]);
        atomicAdd(&lf2[r], acc * ao[TT + c]);
    }
    __syncthreads();
    if (tid < 12) {
        f1o[blk * 12 + tid] = lf1[tid];
        f2o[blk * 12 + tid] = lf2[tid];
    }
}

// ---------------------------------------------------------------------------
// Output-layer attention + elu.  One wave per (b, s<S).  Neighbor lists are
// rebuilt from the bit-packed adjacency written by k_attn1.
// ---------------------------------------------------------------------------
__global__ __launch_bounds__(64) void k_attn2(
    const unsigned long long* __restrict__ packed,
    const float* __restrict__ h2, const float* __restrict__ f1o,
    const float* __restrict__ f2o, float* __restrict__ out2k)
{
    __shared__ int   nbr[NN];
    __shared__ float ep[NN];
    const int lane = threadIdx.x;
    const int blk = blockIdx.x;                 // b*S + s
    const int b = blk / SS, s = blk - b * SS;
    const int n = b * NN + s;
    unsigned long long w64 = (lane < 12) ? packed[(size_t)n * 12 + lane] : 0ULL;
    int pc = __popcll(w64);
    int inc = pc;
    #pragma unroll
    for (int d = 1; d < 16; d <<= 1) {
        int t = __shfl_up(inc, d, 16);
        if ((lane & 15) >= d) inc += t;
    }
    const int C = __shfl(inc, 11);
    int off = inc - pc;
    while (w64) {
        int bit = __builtin_ctzll(w64);
        nbr[off++] = lane * 64 + bit;
        w64 &= w64 - 1;
    }
    __syncthreads();
    const float f1 = f1o[n];
    const float* f2p = f2o + b * NN;
    float mx = -3.0e38f;
    for (int t = lane; t < C; t += 64) {
        int j = nbr[t];
        float e = f1 + f2p[j];
        e = (e >= 0.f) ? e : 0.2f * e;
        ep[t] = e;
        mx = fmaxf(mx, e);
    }
    mx = wred_max(mx);
    float sum = 0.f;
    for (int t = lane; t < C; t += 64) {
        float p = __expf(ep[t] - mx);
        ep[t] = p;
        sum += p;
    }
    sum = wred_sum(sum);
    const float* h2b = h2 + (size_t)b * NN * TT + ((lane < TT) ? lane : 0);
    float ac0 = 0.f, ac1 = 0.f, ac2 = 0.f, ac3 = 0.f;
    int t = 0;
    for (; t + 3 < C; t += 4) {
        int j0 = nbr[t], j1 = nbr[t + 1], j2 = nbr[t + 2], j3 = nbr[t + 3];
        float p0 = ep[t], p1 = ep[t + 1], p2 = ep[t + 2], p3 = ep[t + 3];
        ac0 = fmaf(p0, h2b[(size_t)j0 * TT], ac0);
        ac1 = fmaf(p1, h2b[(size_t)j1 * TT], ac1);
        ac2 = fmaf(p2, h2b[(size_t)j2 * TT], ac2);
        ac3 = fmaf(p3, h2b[(size_t)j3 * TT], ac3);
    }
    for (; t < C; ++t) ac0 = fmaf(ep[t], h2b[(size_t)nbr[t] * TT], ac0);
    if (lane < TT) {
        float r = ((ac0 + ac1) + (ac2 + ac3)) / sum;
        r = (r > 0.f) ? r : expm1f(r);
        out2k[(size_t)blk * TT + lane] = r;
    }
}

// ---------------------------------------------------------------------------
// feats = fuse_w[0]*(lstm_feat@h2h_W^T + b) + sum_k fuse_w[k+1]*out2_k
// ---------------------------------------------------------------------------
__global__ __launch_bounds__(64) void k_fuse(
    const float* __restrict__ gat_in, const float* __restrict__ h2h_W,
    const float* __restrict__ h2h_b, const float* __restrict__ fuse_w,
    const float* __restrict__ out2, float* __restrict__ feats)
{
    __shared__ float row[DD];
    const int lane = threadIdx.x;
    const int blk = blockIdx.x;                 // b*S + s
    const int b = blk / SS, s = blk - b * SS;
    const float* src = gat_in + ((size_t)b * NN + s) * DD;
    row[lane] = src[lane];
    row[lane + 64] = src[lane + 64];
    __syncthreads();
    if (lane < TT) {
        float acc = h2h_b[lane];
        const float4* w4 = (const float4*)&h2h_W[lane * DD];
        const float4* r4 = (const float4*)row;
        #pragma unroll 8
        for (int d4 = 0; d4 < 32; ++d4) {
            float4 w = w4[d4]; float4 v = r4[d4];
            acc = fmaf(w.x, v.x, acc); acc = fmaf(w.y, v.y, acc);
            acc = fmaf(w.z, v.z, acc); acc = fmaf(w.w, v.w, acc);
        }
        size_t o = (size_t)blk * TT + lane;
        feats[o] = fuse_w[0] * acc + fuse_w[1] * out2[o]
                 + fuse_w[2] * out2[(size_t)BS * TT + o]
                 + fuse_w[3] * out2[2 * (size_t)BS * TT + o];
    }
}

// ---------------------------------------------------------------------------
// Viterbi decode.  One wave per batch.  Lanes = (p-group 0..2) x (c 0..20).
// ---------------------------------------------------------------------------
__global__ __launch_bounds__(64) void k_vit(
    const float* __restrict__ feats, const float* __restrict__ trans,
    int* __restrict__ out)
{
    __shared__ float part[24];
    __shared__ unsigned char bp[SS - 1][24];
    const int lane = threadIdx.x;
    const int b = blockIdx.x;
    const int pg = lane / TT;                 // 0,1,2 (lane 63 idle)
    const int c = lane - pg * TT;
    const bool act = (pg < 3);
    const int p0 = pg * 7;
    float tc[7];
    if (act) {
        #pragma unroll
        for (int u = 0; u < 7; ++u) tc[u] = trans[(p0 + u) * TT + c];
    }
    if (lane < TT) part[lane] = feats[((size_t)b * SS) * TT + lane] + trans[19 * TT + lane];
    if (lane >= TT && lane < 24) part[lane] = -3.0e38f;
    __syncthreads();
    for (int t = 1; t < SS; ++t) {
        float best = -3.0e38f; int bi = 0;
        if (act) {
            #pragma unroll
            for (int u = 0; u < 7; ++u) {
                float v = part[p0 + u] + tc[u];
                if (v > best) { best = v; bi = p0 + u; }
            }
        }
        float bv1 = __shfl(best, lane + 21);
        int   bi1 = __shfl(bi,   lane + 21);
        float bv2 = __shfl(best, lane + 42);
        int   bi2 = __shfl(bi,   lane + 42);
        if (lane < TT) {
            if (bv1 > best) { best = bv1; bi = bi1; }
            if (bv2 > best) { best = bv2; bi = bi2; }
            bp[t - 1][lane] = (unsigned char)bi;
            part[lane] = best + feats[((size_t)b * SS + t) * TT + lane];
        }
        __syncthreads();
    }
    float fv = (lane < TT) ? part[lane] + trans[lane * TT + 20] : -3.0e38f;
    int fi = (lane < TT) ? lane : 0;
    #pragma unroll
    for (int o = 32; o > 0; o >>= 1) {
        float ov = __shfl_xor(fv, o);
        int oi = __shfl_xor(fi, o);
        if (ov > fv || (ov == fv && oi < fi)) { fv = ov; fi = oi; }
    }
    __syncthreads();
    if (lane == 0) {
        int cur = fi;
        out[b * SS + SS - 1] = cur;
        for (int u = SS - 2; u >= 0; --u) {
            cur = bp[u][cur];
            out[b * SS + u] = cur;
        }
    }
}

// ---------------------------------------------------------------------------
extern "C" void kernel_launch(void* const* d_in, const int* in_sizes, int n_in,
                              void* d_out, int out_size, void* d_ws, size_t ws_size,
                              hipStream_t stream) {
    (void)in_sizes; (void)n_in; (void)out_size; (void)ws_size;
    const int*   batch_char = (const int*)d_in[0];
    const int*   gaz_list   = (const int*)d_in[2];
    const int*   graphs[3]  = {(const int*)d_in[3], (const int*)d_in[4], (const int*)d_in[5]};
    const float* char_table = (const float*)d_in[7];
    const float* gaz_table  = (const float*)d_in[8];
    const float* w_ih_f = (const float*)d_in[9];
    const float* w_hh_f = (const float*)d_in[10];
    const float* b_f    = (const float*)d_in[11];
    const float* w_ih_b = (const float*)d_in[12];
    const float* w_hh_b = (const float*)d_in[13];
    const float* b_b    = (const float*)d_in[14];
    const float* h2h_W  = (const float*)d_in[15];
    const float* h2h_b  = (const float*)d_in[16];
    const float* gat_Wh = (const float*)d_in[17];
    const float* gat_ah = (const float*)d_in[18];
    const float* gat_Wo = (const float*)d_in[19];
    const float* gat_ao = (const float*)d_in[20];
    const float* fuse_w = (const float*)d_in[21];
    const float* trans  = (const float*)d_in[22];

    float* ws = (float*)d_ws;
    float* gat_in = ws;                         // 1,572,864
    float* xw_f   = gat_in + 1572864;           // 1,572,864
    float* xw_b   = xw_f   + 1572864;           // 1,572,864
    float* h1     = xw_b   + 1572864;           // 3,145,728
    float* out1   = h1     + 3145728;           // 3,145,728
    float* h2     = out1   + 3145728;           //   258,048
    float* f1g    = h2     + 258048;            //    49,152
    float* f2g    = f1g    + 49152;             //    49,152
    float* f1o    = f2g    + 49152;             //    12,288
    float* f2o    = f1o    + 12288;             //    12,288
    float* out2   = f2o    + 12288;             //   387,072
    float* feats  = out2   + 387072;            //   129,024
    unsigned long long* packed = (unsigned long long*)(feats + 129024);  // 98,304 u64

    k_xw<<<dim3(96, 8), 256, 0, stream>>>(batch_char, char_table, w_ih_f, b_f,
                                          w_ih_b, b_b, xw_f, xw_b);
    k_gaz<<<3072, 256, 0, stream>>>(gaz_list, gaz_table, gat_in);
    k_lstm<<<32, 64, 0, stream>>>(xw_f, xw_b, w_hh_f, w_hh_b, gat_in);
    for (int k = 0; k < 3; ++k) {
        k_p1<<<dim3(192, 4), 256, 0, stream>>>(gat_in, gat_Wh, gat_ah, k, h1, f1g, f2g);
        k_attn1<<<BN, 256, 0, stream>>>(graphs[k], h1, f1g, f2g, out1, packed);
        k_p2<<<1024, 256, 0, stream>>>(out1, gat_Wo, gat_ao, k, h2, f1o, f2o);
        k_attn2<<<BS, 64, 0, stream>>>(packed, h2, f1o, f2o, out2 + (size_t)k * BS * TT);
    }
    k_fuse<<<BS, 64, 0, stream>>>(gat_in, h2h_W, h2h_b, fuse_w, out2, feats);
    k_vit<<<BB, 64, 0, stream>>>(feats, trans, (int*)d_out);
}

// Round 6
// 924.692 us; speedup vs baseline: 1.2362x; 1.2362x over previous
//
#include <hip/hip_runtime.h>
#include <hip/hip_bf16.h>
#include <cstdint>
#include <cstddef>

// Problem constants (match reference)
#define BB 16
#define SS 384
#define GG 384
#define NN 768          // S + G
#define DD 128
#define EC 100
#define TT 21
#define NHEADS 4
#define BN (BB*NN)      // 12288
#define BS (BB*SS)      // 6144

// mega-kernel block layout: [0,32) LSTM, [32,3104) gaz, [3104, 3104+3*BN) pack
#define GAZ_BASE  32
#define PACK_BASE (32 + 3072)
#define PRE_GRID  (PACK_BASE + 3 * BN)

typedef float v2f __attribute__((ext_vector_type(2)));

__device__ __forceinline__ float sigf(float x) { return 1.0f / (1.0f + __expf(-x)); }
__device__ __forceinline__ float tanh_fast(float x) {
    // 1 - 2/(exp(2x)+1); exp overflow -> inf -> 1, underflow -> 0 -> -1
    return 1.0f - 2.0f / (__expf(2.0f * x) + 1.0f);
}
__device__ __forceinline__ float wred_max(float v) {
    #pragma unroll
    for (int o = 32; o > 0; o >>= 1) v = fmaxf(v, __shfl_xor(v, o));
    return v;
}
__device__ __forceinline__ float wred_sum(float v) {
    #pragma unroll
    for (int o = 32; o > 0; o >>= 1) v += __shfl_xor(v, o);
    return v;
}

// ---------------------------------------------------------------------------
// xw = emb @ w_ih^T + b for both directions.  Tiled GEMM with char gather.
// grid (96 row-tiles, 8): blockIdx.y -> dir(2) x gate-tile(4).  64x64 tiles.
// ---------------------------------------------------------------------------
__global__ __launch_bounds__(256) void k_xw(
    const int* __restrict__ batch_char, const float* __restrict__ char_table,
    const float* __restrict__ w_ih_f, const float* __restrict__ b_f,
    const float* __restrict__ w_ih_b, const float* __restrict__ b_b,
    float* __restrict__ xw_f, float* __restrict__ xw_b)
{
    __shared__ float At[EC * 68];   // [e][row]
    __shared__ float Bt[EC * 68];   // [e][gate]
    __shared__ int   chs[64];
    const int tid = threadIdx.x;
    const int rt  = blockIdx.x;             // row tile (64 rows of B*S)
    const int ot  = blockIdx.y;             // dir*4 + gate tile
    const int dir = ot >> 2, gt = ot & 3;
    const float* wih  = dir ? w_ih_b : w_ih_f;
    const float* bias = dir ? b_b    : b_f;
    float*       out  = dir ? xw_b   : xw_f;

    if (tid < 64) chs[tid] = batch_char[rt * 64 + tid];
    __syncthreads();
    for (int idx = tid; idx < 64 * EC; idx += 256) {
        int r = idx / EC, e = idx - r * EC;
        At[e * 68 + r] = char_table[(size_t)chs[r] * EC + e];
        Bt[e * 68 + r] = wih[(size_t)(gt * 64 + r) * EC + e];
    }
    __syncthreads();

    const int ty = tid >> 4, tx = tid & 15;
    const int r0 = ty * 4, c0 = tx * 4;
    float acc[4][4] = {};
    #pragma unroll 4
    for (int e = 0; e < EC; ++e) {
        float4 a = *(const float4*)&At[e * 68 + r0];
        float4 bv = *(const float4*)&Bt[e * 68 + c0];
        float av[4] = {a.x, a.y, a.z, a.w};
        float bb[4] = {bv.x, bv.y, bv.z, bv.w};
        #pragma unroll
        for (int i = 0; i < 4; ++i)
            #pragma unroll
            for (int j = 0; j < 4; ++j) acc[i][j] = fmaf(av[i], bb[j], acc[i][j]);
    }
    #pragma unroll
    for (int i = 0; i < 4; ++i) {
        int row = rt * 64 + r0 + i;
        int gc  = gt * 64 + c0;
        float4 o;
        o.x = acc[i][0] + bias[gc + 0];
        o.y = acc[i][1] + bias[gc + 1];
        o.z = acc[i][2] + bias[gc + 2];
        o.w = acc[i][3] + bias[gc + 3];
        *(float4*)&out[(size_t)row * 256 + gc] = o;
    }
}

// ---------------------------------------------------------------------------
// Mega-kernel: BiLSTM scan (blocks 0..31, the R0 200us version) + gaz gather
// (blocks 32..3103) + adjacency ballot-pack for all 3 graphs (blocks 3104+).
// The gaz/pack work runs on the 224 CUs that the 32 LSTM blocks leave idle,
// i.e. inside the LSTM's ~200us shadow -- effectively free, and it removes
// the 113MB adjacency read + ballot phase from the 3x k_attn1 critical path.
// No inter-block dependencies (G16-safe; dispatch order irrelevant for
// correctness).  LSTM blocks have the lowest indices so they dispatch first.
// ---------------------------------------------------------------------------
__global__ __launch_bounds__(256) void k_pre(
    const float* __restrict__ xw_f, const float* __restrict__ xw_b,
    const float* __restrict__ w_hh_f, const float* __restrict__ w_hh_b,
    float* __restrict__ gat_in,
    const int* __restrict__ gaz_list, const float* __restrict__ gaz_table,
    const int* __restrict__ adj0, const int* __restrict__ adj1,
    const int* __restrict__ adj2, unsigned long long* __restrict__ packed)
{
    __shared__ float part[2][4][64][4];   // [buf][wave][unit][g4] (LSTM only)
    __shared__ float hbuf[4][64];         // per-wave private copy of h
    const int bid = blockIdx.x;
    const int tid = threadIdx.x;

    if (bid < 32) {
        // ------- BiLSTM scan: R0-verbatim (measured 200.8us) -------
        const int wv = tid >> 6, lane = tid & 63;
        const int b = bid >> 1, dir = bid & 1;
        const float* xw  = (dir ? xw_b : xw_f) + (size_t)b * SS * 256;
        const float* whh = dir ? w_hh_b : w_hh_f;
        v2f w2[4][8];
        #pragma unroll
        for (int g4 = 0; g4 < 4; ++g4) {
            const float* r = whh + (size_t)(g4 * 64 + lane) * 64 + 16 * wv;
            #pragma unroll
            for (int jj = 0; jj < 8; ++jj) w2[g4][jj] = v2f{r[2 * jj], r[2 * jj + 1]};
        }
        hbuf[wv][lane] = 0.f;                 // own-wave copy; in-order LDS
        float c = 0.f;
        int buf = 0;
        const int t0 = dir ? (SS - 1) : 0;
        float x0 = xw[t0 * 256 +   0 + lane];
        float x1 = xw[t0 * 256 +  64 + lane];
        float x2 = xw[t0 * 256 + 128 + lane];
        float x3 = xw[t0 * 256 + 192 + lane];
        const v2f* h2p = (const v2f*)&hbuf[wv][16 * wv];   // 8 v2f chunk
        for (int tt = 0; tt < SS; ++tt) {
            const int t = dir ? (SS - 1 - tt) : tt;
            const int tn = dir ? (t - 1) : (t + 1);
            v2f a0 = v2f{0.f, 0.f}, a1 = v2f{0.f, 0.f}, a2 = v2f{0.f, 0.f}, a3 = v2f{0.f, 0.f};
            #pragma unroll
            for (int jj = 0; jj < 8; ++jj) {
                v2f hv = h2p[jj];
                a0 = __builtin_elementwise_fma(hv, w2[0][jj], a0);
                a1 = __builtin_elementwise_fma(hv, w2[1][jj], a1);
                a2 = __builtin_elementwise_fma(hv, w2[2][jj], a2);
                a3 = __builtin_elementwise_fma(hv, w2[3][jj], a3);
            }
            float4 pw;
            pw.x = a0.x + a0.y; pw.y = a1.x + a1.y;
            pw.z = a2.x + a2.y; pw.w = a3.x + a3.y;
            *(float4*)part[buf][wv][lane] = pw;
            float nx0 = 0.f, nx1 = 0.f, nx2 = 0.f, nx3 = 0.f;
            if (tt + 1 < SS) {
                nx0 = xw[tn * 256 +   0 + lane];
                nx1 = xw[tn * 256 +  64 + lane];
                nx2 = xw[tn * 256 + 128 + lane];
                nx3 = xw[tn * 256 + 192 + lane];
            }
            __syncthreads();
            float4 p0 = *(const float4*)part[buf][0][lane];
            float4 p1 = *(const float4*)part[buf][1][lane];
            float4 p2 = *(const float4*)part[buf][2][lane];
            float4 p3 = *(const float4*)part[buf][3][lane];
            float gi = ((p0.x + p1.x) + (p2.x + p3.x)) + x0;
            float gf = ((p0.y + p1.y) + (p2.y + p3.y)) + x1;
            float gg = ((p0.z + p1.z) + (p2.z + p3.z)) + x2;
            float go = ((p0.w + p1.w) + (p2.w + p3.w)) + x3;
            float nc = sigf(gf) * c + sigf(gi) * tanh_fast(gg);
            float nh = sigf(go) * tanh_fast(nc);
            c = nc;
            hbuf[wv][lane] = nh;              // own-wave copy; read next step
            if (wv == 0) gat_in[((size_t)b * NN + t) * DD + dir * 64 + lane] = nh;
            x0 = nx0; x1 = nx1; x2 = nx2; x3 = nx3;
            buf ^= 1;
        }
    } else if (bid < PACK_BASE) {
        // ------- gaz embedding gather into gat_in rows [S, N) -------
        int idx = (bid - GAZ_BASE) * 256 + tid;        // B*G*128 total
        int d = idx & 127;
        int rest = idx >> 7;
        int g = rest % GG;
        int b = rest / GG;
        float v = gaz_table[(size_t)gaz_list[b * GG + g] * DD + d];
        gat_in[((size_t)b * NN + SS + g) * DD + d] = v;
    } else {
        // ------- adjacency ballot-pack, all 3 graphs -------
        const int row = bid - PACK_BASE;               // 0 .. 3*BN-1
        const int k = row / BN, n = row - k * BN;
        const int* adjk = (k == 0) ? adj0 : ((k == 1) ? adj1 : adj2);
        const int wave = tid >> 6, lane = tid & 63;
        #pragma unroll
        for (int it = 0; it < 3; ++it) {
            int j = it * 256 + tid;
            unsigned long long m = __ballot(adjk[(size_t)n * NN + j] > 0);
            if (lane == 0)
                packed[((size_t)k * BN + n) * 12 + it * 4 + wave] = m;
        }
    }
}

// ---------------------------------------------------------------------------
// GAT layer-1 projection: h1 = gat_in @ Wh[k][hd] (+ per-row f1/f2 dots).
// grid (192 row-tiles, 4 heads).  64x64 tile, K=128 in 2 phases of 64.
// ---------------------------------------------------------------------------
__global__ __launch_bounds__(256) void k_p1(
    const float* __restrict__ gat_in, const float* __restrict__ gat_Wh,
    const float* __restrict__ gat_ah, int k,
    float* __restrict__ h1, float* __restrict__ f1g, float* __restrict__ f2g)
{
    __shared__ float At[64 * 68];
    __shared__ float Bt[64 * 68];
    __shared__ float sf1[64], sf2[64];
    const int tid = threadIdx.x;
    const int rt = blockIdx.x, hd = blockIdx.y;
    if (tid < 64) { sf1[tid] = 0.f; sf2[tid] = 0.f; }
    const float* W = gat_Wh + ((size_t)(k * NHEADS + hd)) * DD * 64;
    const int ty = tid >> 4, tx = tid & 15;
    const int r0 = ty * 4, c0 = tx * 4;
    float acc[4][4] = {};
    for (int ph = 0; ph < 2; ++ph) {
        __syncthreads();
        for (int idx = tid; idx < 64 * 64; idx += 256) {
            int r = idx >> 6, e = idx & 63;
            At[e * 68 + r] = gat_in[((size_t)(rt * 64 + r)) * DD + ph * 64 + e];
            Bt[e * 68 + r] = W[(size_t)(ph * 64 + e) * 64 + r];
        }
        __syncthreads();
        #pragma unroll 4
        for (int e = 0; e < 64; ++e) {
            float4 a = *(const float4*)&At[e * 68 + r0];
            float4 bv = *(const float4*)&Bt[e * 68 + c0];
            float av[4] = {a.x, a.y, a.z, a.w};
            float bb[4] = {bv.x, bv.y, bv.z, bv.w};
            #pragma unroll
            for (int i = 0; i < 4; ++i)
                #pragma unroll
                for (int j = 0; j < 4; ++j) acc[i][j] = fmaf(av[i], bb[j], acc[i][j]);
        }
    }
    const float* ah = gat_ah + (size_t)(k * NHEADS + hd) * 128;
    float a1[4], a2[4];
    #pragma unroll
    for (int j = 0; j < 4; ++j) { a1[j] = ah[c0 + j]; a2[j] = ah[64 + c0 + j]; }
    #pragma unroll
    for (int i = 0; i < 4; ++i) {
        int n = rt * 64 + r0 + i;
        float4 o = make_float4(acc[i][0], acc[i][1], acc[i][2], acc[i][3]);
        *(float4*)&h1[((size_t)n * NHEADS + hd) * 64 + c0] = o;
        float p1 = acc[i][0] * a1[0] + acc[i][1] * a1[1] + acc[i][2] * a1[2] + acc[i][3] * a1[3];
        float p2 = acc[i][0] * a2[0] + acc[i][1] * a2[1] + acc[i][2] * a2[2] + acc[i][3] * a2[3];
        atomicAdd(&sf1[r0 + i], p1);
        atomicAdd(&sf2[r0 + i], p2);
    }
    __syncthreads();
    if (tid < 64) {
        f1g[hd * BN + rt * 64 + tid] = sf1[tid];
        f2g[hd * BN + rt * 64 + tid] = sf2[tid];
    }
}

// ---------------------------------------------------------------------------
// GAT layer-1 attention (sparse).  One block per row n=(b,i); wave = head.
// Neighbor masks are precomputed by k_pre (96B read instead of 3KB adj,
// no ballot phase, one barrier fewer).  Compaction/extraction order is
// identical to the previous version -> bitwise-identical results.
// ---------------------------------------------------------------------------
__global__ __launch_bounds__(256) void k_attn1(
    const unsigned long long* __restrict__ packedk, const float* __restrict__ h1,
    const float* __restrict__ f1g, const float* __restrict__ f2g,
    float* __restrict__ out1)
{
    __shared__ int   nbr[NN];
    __shared__ float ep[NHEADS][NN];
    __shared__ int cntS;
    const int tid = threadIdx.x, wave = tid >> 6, lane = tid & 63;
    const int n = blockIdx.x;
    const int b = n / NN;
    if (wave == 0) {
        unsigned long long m = (lane < 12) ? packedk[(size_t)n * 12 + lane] : 0ULL;
        int pc = __popcll(m);
        int inc = pc;
        #pragma unroll
        for (int d = 1; d < 16; d <<= 1) { int t = __shfl_up(inc, d); if (lane >= d) inc += t; }
        int C = __shfl(inc, 11);
        if (lane == 0) cntS = C;
        int off = inc - pc;
        while (m) {
            int bit = __builtin_ctzll(m);
            nbr[off++] = lane * 64 + bit;
            m &= m - 1;
        }
    }
    __syncthreads();
    const int C = cntS;
    const int hd = wave;
    const float f1 = f1g[hd * BN + n];
    const float* f2p = f2g + hd * BN + b * NN;
    float mx = -3.0e38f;
    for (int t = lane; t < C; t += 64) {
        float e = f1 + f2p[nbr[t]];
        e = (e >= 0.f) ? e : 0.2f * e;
        ep[hd][t] = e;
        mx = fmaxf(mx, e);
    }
    mx = wred_max(mx);
    float sum = 0.f;
    for (int t = lane; t < C; t += 64) {
        float p = __expf(ep[hd][t] - mx);
        ep[hd][t] = p;
        sum += p;
    }
    sum = wred_sum(sum);
    const float* hb = h1 + (size_t)b * NN * (NHEADS * 64) + hd * 64 + lane;
    float ac0 = 0.f, ac1 = 0.f, ac2 = 0.f, ac3 = 0.f;
    int t = 0;
    for (; t + 3 < C; t += 4) {
        int j0 = nbr[t], j1 = nbr[t + 1], j2 = nbr[t + 2], j3 = nbr[t + 3];
        float p0 = ep[hd][t], p1 = ep[hd][t + 1], p2 = ep[hd][t + 2], p3 = ep[hd][t + 3];
        ac0 = fmaf(p0, hb[(size_t)j0 * 256], ac0);
        ac1 = fmaf(p1, hb[(size_t)j1 * 256], ac1);
        ac2 = fmaf(p2, hb[(size_t)j2 * 256], ac2);
        ac3 = fmaf(p3, hb[(size_t)j3 * 256], ac3);
    }
    for (; t < C; ++t) ac0 = fmaf(ep[hd][t], hb[(size_t)nbr[t] * 256], ac0);
    float r = ((ac0 + ac1) + (ac2 + ac3)) / sum;
    r = (r > 0.f) ? r : expm1f(r);
    out1[(size_t)n * 256 + hd * 64 + lane] = r;
}

// ---------------------------------------------------------------------------
// Output-layer projection: h2 = out1 @ Wo[k]  (+ f1o/f2o dots).  12 rows/block.
// ---------------------------------------------------------------------------
__global__ __launch_bounds__(256) void k_p2(
    const float* __restrict__ out1, const float* __restrict__ gat_Wo,
    const float* __restrict__ gat_ao, int k,
    float* __restrict__ h2, float* __restrict__ f1o, float* __restrict__ f2o)
{
    __shared__ float ld[12 * 256];
    __shared__ float lf1[12], lf2[12];
    const int tid = threadIdx.x;
    const int blk = blockIdx.x;
    if (tid < 12) { lf1[tid] = 0.f; lf2[tid] = 0.f; }
    for (int idx = tid; idx < 12 * 256; idx += 256)
        ld[idx] = out1[(size_t)blk * 12 * 256 + idx];
    __syncthreads();
    if (tid < 252) {
        const int r = tid / TT, c = tid - r * TT;
        const float* Wo = gat_Wo + (size_t)k * 256 * TT;
        const float4* row4 = (const float4*)&ld[r * 256];
        float acc = 0.f;
        #pragma unroll 8
        for (int q4 = 0; q4 < 64; ++q4) {
            float4 v = row4[q4];
            int q = q4 * 4;
            acc = fmaf(v.x, Wo[(q + 0) * TT + c], acc);
            acc = fmaf(v.y, Wo[(q + 1) * TT + c], acc);
            acc = fmaf(v.z, Wo[(q + 2) * TT + c], acc);
            acc = fmaf(v.w, Wo[(q + 3) * TT + c], acc);
        }
        const int n = blk * 12 + r;
        h2[(size_t)n * TT + c] = acc;
        const float* ao = gat_ao + k * 2 * TT;
        atomicAdd(&lf1[r], acc * ao[c]);
        atomicAdd(&lf2[r], acc * ao[TT + c]);
    }
    __syncthreads();
    if (tid < 12) {
        f1o[blk * 12 + tid] = lf1[tid];
        f2o[blk * 12 + tid] = lf2[tid];
    }
}

// ---------------------------------------------------------------------------
// Output-layer attention + elu.  One wave per (b, s<S).  Neighbor lists are
// rebuilt from the bit-packed adjacency written by k_pre.
// ---------------------------------------------------------------------------
__global__ __launch_bounds__(64) void k_attn2(
    const unsigned long long* __restrict__ packedk,
    const float* __restrict__ h2, const float* __restrict__ f1o,
    const float* __restrict__ f2o, float* __restrict__ out2k)
{
    __shared__ int   nbr[NN];
    __shared__ float ep[NN];
    const int lane = threadIdx.x;
    const int blk = blockIdx.x;                 // b*S + s
    const int b = blk / SS, s = blk - b * SS;
    const int n = b * NN + s;
    unsigned long long w64 = (lane < 12) ? packedk[(size_t)n * 12 + lane] : 0ULL;
    int pc = __popcll(w64);
    int inc = pc;
    #pragma unroll
    for (int d = 1; d < 16; d <<= 1) {
        int t = __shfl_up(inc, d, 16);
        if ((lane & 15) >= d) inc += t;
    }
    const int C = __shfl(inc, 11);
    int off = inc - pc;
    while (w64) {
        int bit = __builtin_ctzll(w64);
        nbr[off++] = lane * 64 + bit;
        w64 &= w64 - 1;
    }
    __syncthreads();
    const float f1 = f1o[n];
    const float* f2p = f2o + b * NN;
    float mx = -3.0e38f;
    for (int t = lane; t < C; t += 64) {
        int j = nbr[t];
        float e = f1 + f2p[j];
        e = (e >= 0.f) ? e : 0.2f * e;
        ep[t] = e;
        mx = fmaxf(mx, e);
    }
    mx = wred_max(mx);
    float sum = 0.f;
    for (int t = lane; t < C; t += 64) {
        float p = __expf(ep[t] - mx);
        ep[t] = p;
        sum += p;
    }
    sum = wred_sum(sum);
    const float* h2b = h2 + (size_t)b * NN * TT + ((lane < TT) ? lane : 0);
    float ac0 = 0.f, ac1 = 0.f, ac2 = 0.f, ac3 = 0.f;
    int t = 0;
    for (; t + 3 < C; t += 4) {
        int j0 = nbr[t], j1 = nbr[t + 1], j2 = nbr[t + 2], j3 = nbr[t + 3];
        float p0 = ep[t], p1 = ep[t + 1], p2 = ep[t + 2], p3 = ep[t + 3];
        ac0 = fmaf(p0, h2b[(size_t)j0 * TT], ac0);
        ac1 = fmaf(p1, h2b[(size_t)j1 * TT], ac1);
        ac2 = fmaf(p2, h2b[(size_t)j2 * TT], ac2);
        ac3 = fmaf(p3, h2b[(size_t)j3 * TT], ac3);
    }
    for (; t < C; ++t) ac0 = fmaf(ep[t], h2b[(size_t)nbr[t] * TT], ac0);
    if (lane < TT) {
        float r = ((ac0 + ac1) + (ac2 + ac3)) / sum;
        r = (r > 0.f) ? r : expm1f(r);
        out2k[(size_t)blk * TT + lane] = r;
    }
}

// ---------------------------------------------------------------------------
// feats = fuse_w[0]*(lstm_feat@h2h_W^T + b) + sum_k fuse_w[k+1]*out2_k
// ---------------------------------------------------------------------------
__global__ __launch_bounds__(64) void k_fuse(
    const float* __restrict__ gat_in, const float* __restrict__ h2h_W,
    const float* __restrict__ h2h_b, const float* __restrict__ fuse_w,
    const float* __restrict__ out2, float* __restrict__ feats)
{
    __shared__ float row[DD];
    const int lane = threadIdx.x;
    const int blk = blockIdx.x;                 // b*S + s
    const int b = blk / SS, s = blk - b * SS;
    const float* src = gat_in + ((size_t)b * NN + s) * DD;
    row[lane] = src[lane];
    row[lane + 64] = src[lane + 64];
    __syncthreads();
    if (lane < TT) {
        float acc = h2h_b[lane];
        const float4* w4 = (const float4*)&h2h_W[lane * DD];
        const float4* r4 = (const float4*)row;
        #pragma unroll 8
        for (int d4 = 0; d4 < 32; ++d4) {
            float4 w = w4[d4]; float4 v = r4[d4];
            acc = fmaf(w.x, v.x, acc); acc = fmaf(w.y, v.y, acc);
            acc = fmaf(w.z, v.z, acc); acc = fmaf(w.w, v.w, acc);
        }
        size_t o = (size_t)blk * TT + lane;
        feats[o] = fuse_w[0] * acc + fuse_w[1] * out2[o]
                 + fuse_w[2] * out2[(size_t)BS * TT + o]
                 + fuse_w[3] * out2[2 * (size_t)BS * TT + o];
    }
}

// ---------------------------------------------------------------------------
// Viterbi decode.  One wave per batch.  Lanes = (p-group 0..2) x (c 0..20).
// Single-wave kernel: part[] kept in registers (shfl instead of LDS round
// trip), no barriers, feats prefetched one step ahead.  Backtrack done in
// 16-step chunks: bulk-load 16 bp rows into registers, then chain through
// them with v_readlane (~8 cyc/step) instead of 383 serial ~120-cyc LDS
// reads.  Same values read/written -> identical output.
// ---------------------------------------------------------------------------
__global__ __launch_bounds__(64) void k_vit(
    const float* __restrict__ feats, const float* __restrict__ trans,
    int* __restrict__ out)
{
    __shared__ unsigned char bp[SS - 1][24];
    const int lane = threadIdx.x;
    const int b = blockIdx.x;
    const int pg = lane / TT;                 // 0,1,2 (lane 63 idle)
    const int c = lane - pg * TT;
    const bool act = (pg < 3);
    const int p0 = pg * 7;
    float tc[7];
    if (act) {
        #pragma unroll
        for (int u = 0; u < 7; ++u) tc[u] = trans[(p0 + u) * TT + c];
    }
    float pr = (lane < TT)
        ? feats[((size_t)b * SS) * TT + lane] + trans[19 * TT + lane]
        : -3.0e38f;
    float nf = (lane < TT) ? feats[((size_t)b * SS + 1) * TT + lane] : 0.f;
    for (int t = 1; t < SS; ++t) {
        float fcur = nf;
        if (t + 1 < SS)
            nf = (lane < TT) ? feats[((size_t)b * SS + t + 1) * TT + lane] : 0.f;
        float pv[7];
        #pragma unroll
        for (int u = 0; u < 7; ++u) pv[u] = __shfl(pr, p0 + u);
        float best = -3.0e38f; int bi = 0;
        if (act) {
            #pragma unroll
            for (int u = 0; u < 7; ++u) {
                float v = pv[u] + tc[u];
                if (v > best) { best = v; bi = p0 + u; }
            }
        }
        float bv1 = __shfl(best, lane + 21);
        int   bi1 = __shfl(bi,   lane + 21);
        float bv2 = __shfl(best, lane + 42);
        int   bi2 = __shfl(bi,   lane + 42);
        if (bv1 > best) { best = bv1; bi = bi1; }
        if (bv2 > best) { best = bv2; bi = bi2; }
        if (lane < TT) {
            bp[t - 1][lane] = (unsigned char)bi;
            pr = best + fcur;
        }
    }
    float fv = (lane < TT) ? pr + trans[lane * TT + 20] : -3.0e38f;
    int fi = (lane < TT) ? lane : 0;
    #pragma unroll
    for (int o = 32; o > 0; o >>= 1) {
        float ov = __shfl_xor(fv, o);
        int oi = __shfl_xor(fi, o);
        if (ov > fv || (ov == fv && oi < fi)) { fv = ov; fi = oi; }
    }
    int curs = __builtin_amdgcn_readfirstlane(fi);
    if (lane == 0) out[b * SS + SS - 1] = curs;
    int u = SS - 2;                           // 382
    // serial remainder so the remaining count is a multiple of 16
    int rem = (u + 1) & 15;                   // 15
    for (int i = 0; i < rem; ++i) {
        int tag = bp[u][curs];                // broadcast LDS read
        curs = __builtin_amdgcn_readfirstlane(tag);
        if (lane == 0) out[b * SS + u] = curs;
        --u;
    }
    const int ll = (lane < 24) ? lane : 0;    // lane = tag for chunk loads
    while (u >= 15) {
        const int base = u - 15;
        int v[16];
        #pragma unroll
        for (int i = 0; i < 16; ++i) v[i] = bp[base + i][ll];
        #pragma unroll
        for (int i = 15; i >= 0; --i) {
            curs = __builtin_amdgcn_readlane(v[i], curs);
            if (lane == 0) out[b * SS + base + i] = curs;
        }
        u = base - 1;
    }
}

// ---------------------------------------------------------------------------
extern "C" void kernel_launch(void* const* d_in, const int* in_sizes, int n_in,
                              void* d_out, int out_size, void* d_ws, size_t ws_size,
                              hipStream_t stream) {
    (void)in_sizes; (void)n_in; (void)out_size; (void)ws_size;
    const int*   batch_char = (const int*)d_in[0];
    const int*   gaz_list   = (const int*)d_in[2];
    const int*   graphs[3]  = {(const int*)d_in[3], (const int*)d_in[4], (const int*)d_in[5]};
    const float* char_table = (const float*)d_in[7];
    const float* gaz_table  = (const float*)d_in[8];
    const float* w_ih_f = (const float*)d_in[9];
    const float* w_hh_f = (const float*)d_in[10];
    const float* b_f    = (const float*)d_in[11];
    const float* w_ih_b = (const float*)d_in[12];
    const float* w_hh_b = (const float*)d_in[13];
    const float* b_b    = (const float*)d_in[14];
    const float* h2h_W  = (const float*)d_in[15];
    const float* h2h_b  = (const float*)d_in[16];
    const float* gat_Wh = (const float*)d_in[17];
    const float* gat_ah = (const float*)d_in[18];
    const float* gat_Wo = (const float*)d_in[19];
    const float* gat_ao = (const float*)d_in[20];
    const float* fuse_w = (const float*)d_in[21];
    const float* trans  = (const float*)d_in[22];

    float* ws = (float*)d_ws;
    float* gat_in = ws;                         // 1,572,864
    float* xw_f   = gat_in + 1572864;           // 1,572,864
    float* xw_b   = xw_f   + 1572864;           // 1,572,864
    float* h1     = xw_b   + 1572864;           // 3,145,728
    float* out1   = h1     + 3145728;           // 3,145,728
    float* h2     = out1   + 3145728;           //   258,048
    float* f1g    = h2     + 258048;            //    49,152
    float* f2g    = f1g    + 49152;             //    49,152
    float* f1o    = f2g    + 49152;             //    12,288
    float* f2o    = f1o    + 12288;             //    12,288
    float* out2   = f2o    + 12288;             //   387,072
    float* feats  = out2   + 387072;            //   129,024
    unsigned long long* packed = (unsigned long long*)(feats + 129024);  // 3*BN*12 u64

    k_xw<<<dim3(96, 8), 256, 0, stream>>>(batch_char, char_table, w_ih_f, b_f,
                                          w_ih_b, b_b, xw_f, xw_b);
    k_pre<<<PRE_GRID, 256, 0, stream>>>(xw_f, xw_b, w_hh_f, w_hh_b, gat_in,
                                        gaz_list, gaz_table,
                                        graphs[0], graphs[1], graphs[2], packed);
    for (int k = 0; k < 3; ++k) {
        const unsigned long long* pk = packed + (size_t)k * BN * 12;
        k_p1<<<dim3(192, 4), 256, 0, stream>>>(gat_in, gat_Wh, gat_ah, k, h1, f1g, f2g);
        k_attn1<<<BN, 256, 0, stream>>>(pk, h1, f1g, f2g, out1);
        k_p2<<<1024, 256, 0, stream>>>(out1, gat_Wo, gat_ao, k, h2, f1o, f2o);
        k_attn2<<<BS, 64, 0, stream>>>(pk, h2, f1o, f2o, out2 + (size_t)k * BS * TT);
    }
    k_fuse<<<BS, 64, 0, stream>>>(gat_in, h2h_W, h2h_b, fuse_w, out2, feats);
    k_vit<<<BB, 64, 0, stream>>>(feats, trans, (int*)d_out);
}

// Round 7
// 880.078 us; speedup vs baseline: 1.2989x; 1.0507x over previous
//
#include <hip/hip_runtime.h>
#include <hip/hip_bf16.h>
#include <cstdint>
#include <cstddef>

// Problem constants (match reference)
#define BB 16
#define SS 384
#define GG 384
#define NN 768          // S + G
#define DD 128
#define EC 100
#define TT 21
#define NHEADS 4
#define BN (BB*NN)      // 12288
#define BS (BB*SS)      // 6144

// mega-kernel block layout: [0,32) LSTM, [32,3104) gaz, [3104, 3104+3*BN) pack
#define GAZ_BASE  32
#define PACK_BASE (32 + 3072)
#define PRE_GRID  (PACK_BASE + 3 * BN)

// per-k buffer sizes (floats / u64)
#define H1SZ   3145728
#define OUT1SZ 3145728
#define H2SZ   258048
#define FGSZ   49152
#define FOSZ   12288
#define OUT2SZ 129024
#define PKSZ   ((size_t)BN * 12)

typedef float v2f __attribute__((ext_vector_type(2)));

__device__ __forceinline__ float sigf(float x) { return 1.0f / (1.0f + __expf(-x)); }
__device__ __forceinline__ float tanh_fast(float x) {
    // 1 - 2/(exp(2x)+1); exp overflow -> inf -> 1, underflow -> 0 -> -1
    return 1.0f - 2.0f / (__expf(2.0f * x) + 1.0f);
}
__device__ __forceinline__ float wred_max(float v) {
    #pragma unroll
    for (int o = 32; o > 0; o >>= 1) v = fmaxf(v, __shfl_xor(v, o));
    return v;
}
__device__ __forceinline__ float wred_sum(float v) {
    #pragma unroll
    for (int o = 32; o > 0; o >>= 1) v += __shfl_xor(v, o);
    return v;
}

// ---------------------------------------------------------------------------
// xw = emb @ w_ih^T + b for both directions.  Tiled GEMM with char gather.
// grid (96 row-tiles, 8): blockIdx.y -> dir(2) x gate-tile(4).  64x64 tiles.
// ---------------------------------------------------------------------------
__global__ __launch_bounds__(256) void k_xw(
    const int* __restrict__ batch_char, const float* __restrict__ char_table,
    const float* __restrict__ w_ih_f, const float* __restrict__ b_f,
    const float* __restrict__ w_ih_b, const float* __restrict__ b_b,
    float* __restrict__ xw_f, float* __restrict__ xw_b)
{
    __shared__ float At[EC * 68];   // [e][row]
    __shared__ float Bt[EC * 68];   // [e][gate]
    __shared__ int   chs[64];
    const int tid = threadIdx.x;
    const int rt  = blockIdx.x;             // row tile (64 rows of B*S)
    const int ot  = blockIdx.y;             // dir*4 + gate tile
    const int dir = ot >> 2, gt = ot & 3;
    const float* wih  = dir ? w_ih_b : w_ih_f;
    const float* bias = dir ? b_b    : b_f;
    float*       out  = dir ? xw_b   : xw_f;

    if (tid < 64) chs[tid] = batch_char[rt * 64 + tid];
    __syncthreads();
    for (int idx = tid; idx < 64 * EC; idx += 256) {
        int r = idx / EC, e = idx - r * EC;
        At[e * 68 + r] = char_table[(size_t)chs[r] * EC + e];
        Bt[e * 68 + r] = wih[(size_t)(gt * 64 + r) * EC + e];
    }
    __syncthreads();

    const int ty = tid >> 4, tx = tid & 15;
    const int r0 = ty * 4, c0 = tx * 4;
    float acc[4][4] = {};
    #pragma unroll 4
    for (int e = 0; e < EC; ++e) {
        float4 a = *(const float4*)&At[e * 68 + r0];
        float4 bv = *(const float4*)&Bt[e * 68 + c0];
        float av[4] = {a.x, a.y, a.z, a.w};
        float bb[4] = {bv.x, bv.y, bv.z, bv.w};
        #pragma unroll
        for (int i = 0; i < 4; ++i)
            #pragma unroll
            for (int j = 0; j < 4; ++j) acc[i][j] = fmaf(av[i], bb[j], acc[i][j]);
    }
    #pragma unroll
    for (int i = 0; i < 4; ++i) {
        int row = rt * 64 + r0 + i;
        int gc  = gt * 64 + c0;
        float4 o;
        o.x = acc[i][0] + bias[gc + 0];
        o.y = acc[i][1] + bias[gc + 1];
        o.z = acc[i][2] + bias[gc + 2];
        o.w = acc[i][3] + bias[gc + 3];
        *(float4*)&out[(size_t)row * 256 + gc] = o;
    }
}

// ---------------------------------------------------------------------------
// Mega-kernel: BiLSTM scan (blocks 0..31, the R0 200us version) + gaz gather
// (blocks 32..3103) + adjacency ballot-pack for all 3 graphs (blocks 3104+).
// The gaz/pack work runs on the 224 CUs the 32 LSTM blocks leave idle.
// ---------------------------------------------------------------------------
__global__ __launch_bounds__(256) void k_pre(
    const float* __restrict__ xw_f, const float* __restrict__ xw_b,
    const float* __restrict__ w_hh_f, const float* __restrict__ w_hh_b,
    float* __restrict__ gat_in,
    const int* __restrict__ gaz_list, const float* __restrict__ gaz_table,
    const int* __restrict__ adj0, const int* __restrict__ adj1,
    const int* __restrict__ adj2, unsigned long long* __restrict__ packed)
{
    __shared__ float part[2][4][64][4];   // [buf][wave][unit][g4] (LSTM only)
    __shared__ float hbuf[4][64];         // per-wave private copy of h
    const int bid = blockIdx.x;
    const int tid = threadIdx.x;

    if (bid < 32) {
        // ------- BiLSTM scan: R0-verbatim (measured 200.8us) -------
        const int wv = tid >> 6, lane = tid & 63;
        const int b = bid >> 1, dir = bid & 1;
        const float* xw  = (dir ? xw_b : xw_f) + (size_t)b * SS * 256;
        const float* whh = dir ? w_hh_b : w_hh_f;
        v2f w2[4][8];
        #pragma unroll
        for (int g4 = 0; g4 < 4; ++g4) {
            const float* r = whh + (size_t)(g4 * 64 + lane) * 64 + 16 * wv;
            #pragma unroll
            for (int jj = 0; jj < 8; ++jj) w2[g4][jj] = v2f{r[2 * jj], r[2 * jj + 1]};
        }
        hbuf[wv][lane] = 0.f;                 // own-wave copy; in-order LDS
        float c = 0.f;
        int buf = 0;
        const int t0 = dir ? (SS - 1) : 0;
        float x0 = xw[t0 * 256 +   0 + lane];
        float x1 = xw[t0 * 256 +  64 + lane];
        float x2 = xw[t0 * 256 + 128 + lane];
        float x3 = xw[t0 * 256 + 192 + lane];
        const v2f* h2p = (const v2f*)&hbuf[wv][16 * wv];   // 8 v2f chunk
        for (int tt = 0; tt < SS; ++tt) {
            const int t = dir ? (SS - 1 - tt) : tt;
            const int tn = dir ? (t - 1) : (t + 1);
            v2f a0 = v2f{0.f, 0.f}, a1 = v2f{0.f, 0.f}, a2 = v2f{0.f, 0.f}, a3 = v2f{0.f, 0.f};
            #pragma unroll
            for (int jj = 0; jj < 8; ++jj) {
                v2f hv = h2p[jj];
                a0 = __builtin_elementwise_fma(hv, w2[0][jj], a0);
                a1 = __builtin_elementwise_fma(hv, w2[1][jj], a1);
                a2 = __builtin_elementwise_fma(hv, w2[2][jj], a2);
                a3 = __builtin_elementwise_fma(hv, w2[3][jj], a3);
            }
            float4 pw;
            pw.x = a0.x + a0.y; pw.y = a1.x + a1.y;
            pw.z = a2.x + a2.y; pw.w = a3.x + a3.y;
            *(float4*)part[buf][wv][lane] = pw;
            float nx0 = 0.f, nx1 = 0.f, nx2 = 0.f, nx3 = 0.f;
            if (tt + 1 < SS) {
                nx0 = xw[tn * 256 +   0 + lane];
                nx1 = xw[tn * 256 +  64 + lane];
                nx2 = xw[tn * 256 + 128 + lane];
                nx3 = xw[tn * 256 + 192 + lane];
            }
            __syncthreads();
            float4 p0 = *(const float4*)part[buf][0][lane];
            float4 p1 = *(const float4*)part[buf][1][lane];
            float4 p2 = *(const float4*)part[buf][2][lane];
            float4 p3 = *(const float4*)part[buf][3][lane];
            float gi = ((p0.x + p1.x) + (p2.x + p3.x)) + x0;
            float gf = ((p0.y + p1.y) + (p2.y + p3.y)) + x1;
            float gg = ((p0.z + p1.z) + (p2.z + p3.z)) + x2;
            float go = ((p0.w + p1.w) + (p2.w + p3.w)) + x3;
            float nc = sigf(gf) * c + sigf(gi) * tanh_fast(gg);
            float nh = sigf(go) * tanh_fast(nc);
            c = nc;
            hbuf[wv][lane] = nh;              // own-wave copy; read next step
            if (wv == 0) gat_in[((size_t)b * NN + t) * DD + dir * 64 + lane] = nh;
            x0 = nx0; x1 = nx1; x2 = nx2; x3 = nx3;
            buf ^= 1;
        }
    } else if (bid < PACK_BASE) {
        // ------- gaz embedding gather into gat_in rows [S, N) -------
        int idx = (bid - GAZ_BASE) * 256 + tid;        // B*G*128 total
        int d = idx & 127;
        int rest = idx >> 7;
        int g = rest % GG;
        int b = rest / GG;
        float v = gaz_table[(size_t)gaz_list[b * GG + g] * DD + d];
        gat_in[((size_t)b * NN + SS + g) * DD + d] = v;
    } else {
        // ------- adjacency ballot-pack, all 3 graphs -------
        const int row = bid - PACK_BASE;               // 0 .. 3*BN-1
        const int k = row / BN, n = row - k * BN;
        const int* adjk = (k == 0) ? adj0 : ((k == 1) ? adj1 : adj2);
        const int wave = tid >> 6, lane = tid & 63;
        #pragma unroll
        for (int it = 0; it < 3; ++it) {
            int j = it * 256 + tid;
            unsigned long long m = __ballot(adjk[(size_t)n * NN + j] > 0);
            if (lane == 0)
                packed[((size_t)k * BN + n) * 12 + it * 4 + wave] = m;
        }
    }
}

// ---------------------------------------------------------------------------
// GAT layer-1 projection: h1 = gat_in @ Wh[k][hd] (+ per-row f1/f2 dots).
// grid (192 row-tiles, 4 heads, Z ks).  k = k0 + blockIdx.z; per-z buffer
// offsets (0 strides in the serial fallback -> identical to R6 behavior).
// ---------------------------------------------------------------------------
__global__ __launch_bounds__(256) void k_p1(
    const float* __restrict__ gat_in, const float* __restrict__ gat_Wh,
    const float* __restrict__ gat_ah, int k0,
    float* __restrict__ h1, float* __restrict__ f1g, float* __restrict__ f2g,
    size_t zh1, size_t zfg)
{
    __shared__ float At[64 * 68];
    __shared__ float Bt[64 * 68];
    __shared__ float sf1[64], sf2[64];
    const int tid = threadIdx.x;
    const int rt = blockIdx.x, hd = blockIdx.y, z = blockIdx.z;
    const int k = k0 + z;
    float* h1p = h1 + (size_t)z * zh1;
    float* f1p = f1g + (size_t)z * zfg;
    float* f2p = f2g + (size_t)z * zfg;
    if (tid < 64) { sf1[tid] = 0.f; sf2[tid] = 0.f; }
    const float* W = gat_Wh + ((size_t)(k * NHEADS + hd)) * DD * 64;
    const int ty = tid >> 4, tx = tid & 15;
    const int r0 = ty * 4, c0 = tx * 4;
    float acc[4][4] = {};
    for (int ph = 0; ph < 2; ++ph) {
        __syncthreads();
        for (int idx = tid; idx < 64 * 64; idx += 256) {
            int r = idx >> 6, e = idx & 63;
            At[e * 68 + r] = gat_in[((size_t)(rt * 64 + r)) * DD + ph * 64 + e];
            Bt[e * 68 + r] = W[(size_t)(ph * 64 + e) * 64 + r];
        }
        __syncthreads();
        #pragma unroll 4
        for (int e = 0; e < 64; ++e) {
            float4 a = *(const float4*)&At[e * 68 + r0];
            float4 bv = *(const float4*)&Bt[e * 68 + c0];
            float av[4] = {a.x, a.y, a.z, a.w};
            float bb[4] = {bv.x, bv.y, bv.z, bv.w};
            #pragma unroll
            for (int i = 0; i < 4; ++i)
                #pragma unroll
                for (int j = 0; j < 4; ++j) acc[i][j] = fmaf(av[i], bb[j], acc[i][j]);
        }
    }
    const float* ah = gat_ah + (size_t)(k * NHEADS + hd) * 128;
    float a1[4], a2[4];
    #pragma unroll
    for (int j = 0; j < 4; ++j) { a1[j] = ah[c0 + j]; a2[j] = ah[64 + c0 + j]; }
    #pragma unroll
    for (int i = 0; i < 4; ++i) {
        int n = rt * 64 + r0 + i;
        float4 o = make_float4(acc[i][0], acc[i][1], acc[i][2], acc[i][3]);
        *(float4*)&h1p[((size_t)n * NHEADS + hd) * 64 + c0] = o;
        float p1 = acc[i][0] * a1[0] + acc[i][1] * a1[1] + acc[i][2] * a1[2] + acc[i][3] * a1[3];
        float p2 = acc[i][0] * a2[0] + acc[i][1] * a2[1] + acc[i][2] * a2[2] + acc[i][3] * a2[3];
        atomicAdd(&sf1[r0 + i], p1);
        atomicAdd(&sf2[r0 + i], p2);
    }
    __syncthreads();
    if (tid < 64) {
        f1p[hd * BN + rt * 64 + tid] = sf1[tid];
        f2p[hd * BN + rt * 64 + tid] = sf2[tid];
    }
}

// ---------------------------------------------------------------------------
// GAT layer-1 attention (sparse).  grid (BN, 1, Z); wave = head.
// ---------------------------------------------------------------------------
__global__ __launch_bounds__(256) void k_attn1(
    const unsigned long long* __restrict__ packed, const float* __restrict__ h1,
    const float* __restrict__ f1g, const float* __restrict__ f2g,
    float* __restrict__ out1,
    size_t zpk, size_t zh1, size_t zfg, size_t zout1)
{
    __shared__ int   nbr[NN];
    __shared__ float ep[NHEADS][NN];
    __shared__ int cntS;
    const int tid = threadIdx.x, wave = tid >> 6, lane = tid & 63;
    const int n = blockIdx.x, z = blockIdx.z;
    const int b = n / NN;
    const unsigned long long* pkp = packed + (size_t)z * zpk;
    const float* h1p = h1 + (size_t)z * zh1;
    const float* f1p = f1g + (size_t)z * zfg;
    const float* f2gp = f2g + (size_t)z * zfg;
    float* out1p = out1 + (size_t)z * zout1;
    if (wave == 0) {
        unsigned long long m = (lane < 12) ? pkp[(size_t)n * 12 + lane] : 0ULL;
        int pc = __popcll(m);
        int inc = pc;
        #pragma unroll
        for (int d = 1; d < 16; d <<= 1) { int t = __shfl_up(inc, d); if (lane >= d) inc += t; }
        int C = __shfl(inc, 11);
        if (lane == 0) cntS = C;
        int off = inc - pc;
        while (m) {
            int bit = __builtin_ctzll(m);
            nbr[off++] = lane * 64 + bit;
            m &= m - 1;
        }
    }
    __syncthreads();
    const int C = cntS;
    const int hd = wave;
    const float f1 = f1p[hd * BN + n];
    const float* f2p = f2gp + hd * BN + b * NN;
    float mx = -3.0e38f;
    for (int t = lane; t < C; t += 64) {
        float e = f1 + f2p[nbr[t]];
        e = (e >= 0.f) ? e : 0.2f * e;
        ep[hd][t] = e;
        mx = fmaxf(mx, e);
    }
    mx = wred_max(mx);
    float sum = 0.f;
    for (int t = lane; t < C; t += 64) {
        float p = __expf(ep[hd][t] - mx);
        ep[hd][t] = p;
        sum += p;
    }
    sum = wred_sum(sum);
    const float* hb = h1p + (size_t)b * NN * (NHEADS * 64) + hd * 64 + lane;
    float ac0 = 0.f, ac1 = 0.f, ac2 = 0.f, ac3 = 0.f;
    int t = 0;
    for (; t + 3 < C; t += 4) {
        int j0 = nbr[t], j1 = nbr[t + 1], j2 = nbr[t + 2], j3 = nbr[t + 3];
        float p0 = ep[hd][t], p1 = ep[hd][t + 1], p2 = ep[hd][t + 2], p3 = ep[hd][t + 3];
        ac0 = fmaf(p0, hb[(size_t)j0 * 256], ac0);
        ac1 = fmaf(p1, hb[(size_t)j1 * 256], ac1);
        ac2 = fmaf(p2, hb[(size_t)j2 * 256], ac2);
        ac3 = fmaf(p3, hb[(size_t)j3 * 256], ac3);
    }
    for (; t < C; ++t) ac0 = fmaf(ep[hd][t], hb[(size_t)nbr[t] * 256], ac0);
    float r = ((ac0 + ac1) + (ac2 + ac3)) / sum;
    r = (r > 0.f) ? r : expm1f(r);
    out1p[(size_t)n * 256 + hd * 64 + lane] = r;
}

// ---------------------------------------------------------------------------
// Output-layer projection: h2 = out1 @ Wo[k].  grid (1024, 1, Z).
// ---------------------------------------------------------------------------
__global__ __launch_bounds__(256) void k_p2(
    const float* __restrict__ out1, const float* __restrict__ gat_Wo,
    const float* __restrict__ gat_ao, int k0,
    float* __restrict__ h2, float* __restrict__ f1o, float* __restrict__ f2o,
    size_t zout1, size_t zh2, size_t zfo)
{
    __shared__ float ld[12 * 256];
    __shared__ float lf1[12], lf2[12];
    const int tid = threadIdx.x;
    const int blk = blockIdx.x, z = blockIdx.z;
    const int k = k0 + z;
    const float* out1p = out1 + (size_t)z * zout1;
    float* h2p = h2 + (size_t)z * zh2;
    float* f1op = f1o + (size_t)z * zfo;
    float* f2op = f2o + (size_t)z * zfo;
    if (tid < 12) { lf1[tid] = 0.f; lf2[tid] = 0.f; }
    for (int idx = tid; idx < 12 * 256; idx += 256)
        ld[idx] = out1p[(size_t)blk * 12 * 256 + idx];
    __syncthreads();
    if (tid < 252) {
        const int r = tid / TT, c = tid - r * TT;
        const float* Wo = gat_Wo + (size_t)k * 256 * TT;
        const float4* row4 = (const float4*)&ld[r * 256];
        float acc = 0.f;
        #pragma unroll 8
        for (int q4 = 0; q4 < 64; ++q4) {
            float4 v = row4[q4];
            int q = q4 * 4;
            acc = fmaf(v.x, Wo[(q + 0) * TT + c], acc);
            acc = fmaf(v.y, Wo[(q + 1) * TT + c], acc);
            acc = fmaf(v.z, Wo[(q + 2) * TT + c], acc);
            acc = fmaf(v.w, Wo[(q + 3) * TT + c], acc);
        }
        const int n = blk * 12 + r;
        h2p[(size_t)n * TT + c] = acc;
        const float* ao = gat_ao + k * 2 * TT;
        atomicAdd(&lf1[r], acc * ao[c]);
        atomicAdd(&lf2[r], acc * ao[TT + c]);
    }
    __syncthreads();
    if (tid < 12) {
        f1op[blk * 12 + tid] = lf1[tid];
        f2op[blk * 12 + tid] = lf2[tid];
    }
}

// ---------------------------------------------------------------------------
// Output-layer attention + elu.  grid (BS, 1, Z); one wave per (b, s<S).
// ---------------------------------------------------------------------------
__global__ __launch_bounds__(64) void k_attn2(
    const unsigned long long* __restrict__ packed,
    const float* __restrict__ h2, const float* __restrict__ f1o,
    const float* __restrict__ f2o, float* __restrict__ out2,
    size_t zpk, size_t zh2, size_t zfo, size_t zout2)
{
    __shared__ int   nbr[NN];
    __shared__ float ep[NN];
    const int lane = threadIdx.x;
    const int blk = blockIdx.x, z = blockIdx.z;  // blk = b*S + s
    const int b = blk / SS, s = blk - b * SS;
    const int n = b * NN + s;
    const unsigned long long* pkp = packed + (size_t)z * zpk;
    const float* h2p = h2 + (size_t)z * zh2;
    const float* f1op = f1o + (size_t)z * zfo;
    const float* f2op = f2o + (size_t)z * zfo;
    float* out2k = out2 + (size_t)z * zout2;
    unsigned long long w64 = (lane < 12) ? pkp[(size_t)n * 12 + lane] : 0ULL;
    int pc = __popcll(w64);
    int inc = pc;
    #pragma unroll
    for (int d = 1; d < 16; d <<= 1) {
        int t = __shfl_up(inc, d, 16);
        if ((lane & 15) >= d) inc += t;
    }
    const int C = __shfl(inc, 11);
    int off = inc - pc;
    while (w64) {
        int bit = __builtin_ctzll(w64);
        nbr[off++] = lane * 64 + bit;
        w64 &= w64 - 1;
    }
    __syncthreads();
    const float f1 = f1op[n];
    const float* f2p = f2op + b * NN;
    float mx = -3.0e38f;
    for (int t = lane; t < C; t += 64) {
        int j = nbr[t];
        float e = f1 + f2p[j];
        e = (e >= 0.f) ? e : 0.2f * e;
        ep[t] = e;
        mx = fmaxf(mx, e);
    }
    mx = wred_max(mx);
    float sum = 0.f;
    for (int t = lane; t < C; t += 64) {
        float p = __expf(ep[t] - mx);
        ep[t] = p;
        sum += p;
    }
    sum = wred_sum(sum);
    const float* h2b = h2p + (size_t)b * NN * TT + ((lane < TT) ? lane : 0);
    float ac0 = 0.f, ac1 = 0.f, ac2 = 0.f, ac3 = 0.f;
    int t = 0;
    for (; t + 3 < C; t += 4) {
        int j0 = nbr[t], j1 = nbr[t + 1], j2 = nbr[t + 2], j3 = nbr[t + 3];
        float p0 = ep[t], p1 = ep[t + 1], p2 = ep[t + 2], p3 = ep[t + 3];
        ac0 = fmaf(p0, h2b[(size_t)j0 * TT], ac0);
        ac1 = fmaf(p1, h2b[(size_t)j1 * TT], ac1);
        ac2 = fmaf(p2, h2b[(size_t)j2 * TT], ac2);
        ac3 = fmaf(p3, h2b[(size_t)j3 * TT], ac3);
    }
    for (; t < C; ++t) ac0 = fmaf(ep[t], h2b[(size_t)nbr[t] * TT], ac0);
    if (lane < TT) {
        float r = ((ac0 + ac1) + (ac2 + ac3)) / sum;
        r = (r > 0.f) ? r : expm1f(r);
        out2k[(size_t)blk * TT + lane] = r;
    }
}

// ---------------------------------------------------------------------------
// feats = fuse_w[0]*(lstm_feat@h2h_W^T + b) + sum_k fuse_w[k+1]*out2_k
// ---------------------------------------------------------------------------
__global__ __launch_bounds__(64) void k_fuse(
    const float* __restrict__ gat_in, const float* __restrict__ h2h_W,
    const float* __restrict__ h2h_b, const float* __restrict__ fuse_w,
    const float* __restrict__ out2, float* __restrict__ feats)
{
    __shared__ float row[DD];
    const int lane = threadIdx.x;
    const int blk = blockIdx.x;                 // b*S + s
    const int b = blk / SS, s = blk - b * SS;
    const float* src = gat_in + ((size_t)b * NN + s) * DD;
    row[lane] = src[lane];
    row[lane + 64] = src[lane + 64];
    __syncthreads();
    if (lane < TT) {
        float acc = h2h_b[lane];
        const float4* w4 = (const float4*)&h2h_W[lane * DD];
        const float4* r4 = (const float4*)row;
        #pragma unroll 8
        for (int d4 = 0; d4 < 32; ++d4) {
            float4 w = w4[d4]; float4 v = r4[d4];
            acc = fmaf(w.x, v.x, acc); acc = fmaf(w.y, v.y, acc);
            acc = fmaf(w.z, v.z, acc); acc = fmaf(w.w, v.w, acc);
        }
        size_t o = (size_t)blk * TT + lane;
        feats[o] = fuse_w[0] * acc + fuse_w[1] * out2[o]
                 + fuse_w[2] * out2[(size_t)BS * TT + o]
                 + fuse_w[3] * out2[2 * (size_t)BS * TT + o];
    }
}

// ---------------------------------------------------------------------------
// Viterbi decode.  One wave per batch; part[] in registers, reg backtrack.
// ---------------------------------------------------------------------------
__global__ __launch_bounds__(64) void k_vit(
    const float* __restrict__ feats, const float* __restrict__ trans,
    int* __restrict__ out)
{
    __shared__ unsigned char bp[SS - 1][24];
    const int lane = threadIdx.x;
    const int b = blockIdx.x;
    const int pg = lane / TT;                 // 0,1,2 (lane 63 idle)
    const int c = lane - pg * TT;
    const bool act = (pg < 3);
    const int p0 = pg * 7;
    float tc[7];
    if (act) {
        #pragma unroll
        for (int u = 0; u < 7; ++u) tc[u] = trans[(p0 + u) * TT + c];
    }
    float pr = (lane < TT)
        ? feats[((size_t)b * SS) * TT + lane] + trans[19 * TT + lane]
        : -3.0e38f;
    float nf = (lane < TT) ? feats[((size_t)b * SS + 1) * TT + lane] : 0.f;
    for (int t = 1; t < SS; ++t) {
        float fcur = nf;
        if (t + 1 < SS)
            nf = (lane < TT) ? feats[((size_t)b * SS + t + 1) * TT + lane] : 0.f;
        float pv[7];
        #pragma unroll
        for (int u = 0; u < 7; ++u) pv[u] = __shfl(pr, p0 + u);
        float best = -3.0e38f; int bi = 0;
        if (act) {
            #pragma unroll
            for (int u = 0; u < 7; ++u) {
                float v = pv[u] + tc[u];
                if (v > best) { best = v; bi = p0 + u; }
            }
        }
        float bv1 = __shfl(best, lane + 21);
        int   bi1 = __shfl(bi,   lane + 21);
        float bv2 = __shfl(best, lane + 42);
        int   bi2 = __shfl(bi,   lane + 42);
        if (bv1 > best) { best = bv1; bi = bi1; }
        if (bv2 > best) { best = bv2; bi = bi2; }
        if (lane < TT) {
            bp[t - 1][lane] = (unsigned char)bi;
            pr = best + fcur;
        }
    }
    float fv = (lane < TT) ? pr + trans[lane * TT + 20] : -3.0e38f;
    int fi = (lane < TT) ? lane : 0;
    #pragma unroll
    for (int o = 32; o > 0; o >>= 1) {
        float ov = __shfl_xor(fv, o);
        int oi = __shfl_xor(fi, o);
        if (ov > fv || (ov == fv && oi < fi)) { fv = ov; fi = oi; }
    }
    int curs = __builtin_amdgcn_readfirstlane(fi);
    if (lane == 0) out[b * SS + SS - 1] = curs;
    int u = SS - 2;                           // 382
    int rem = (u + 1) & 15;                   // 15
    for (int i = 0; i < rem; ++i) {
        int tag = bp[u][curs];                // broadcast LDS read
        curs = __builtin_amdgcn_readfirstlane(tag);
        if (lane == 0) out[b * SS + u] = curs;
        --u;
    }
    const int ll = (lane < 24) ? lane : 0;    // lane = tag for chunk loads
    while (u >= 15) {
        const int base = u - 15;
        int v[16];
        #pragma unroll
        for (int i = 0; i < 16; ++i) v[i] = bp[base + i][ll];
        #pragma unroll
        for (int i = 15; i >= 0; --i) {
            curs = __builtin_amdgcn_readlane(v[i], curs);
            if (lane == 0) out[b * SS + base + i] = curs;
        }
        u = base - 1;
    }
}

// ---------------------------------------------------------------------------
extern "C" void kernel_launch(void* const* d_in, const int* in_sizes, int n_in,
                              void* d_out, int out_size, void* d_ws, size_t ws_size,
                              hipStream_t stream) {
    (void)in_sizes; (void)n_in; (void)out_size;
    const int*   batch_char = (const int*)d_in[0];
    const int*   gaz_list   = (const int*)d_in[2];
    const int*   graphs[3]  = {(const int*)d_in[3], (const int*)d_in[4], (const int*)d_in[5]};
    const float* char_table = (const float*)d_in[7];
    const float* gaz_table  = (const float*)d_in[8];
    const float* w_ih_f = (const float*)d_in[9];
    const float* w_hh_f = (const float*)d_in[10];
    const float* b_f    = (const float*)d_in[11];
    const float* w_ih_b = (const float*)d_in[12];
    const float* w_hh_b = (const float*)d_in[13];
    const float* b_b    = (const float*)d_in[14];
    const float* h2h_W  = (const float*)d_in[15];
    const float* h2h_b  = (const float*)d_in[16];
    const float* gat_Wh = (const float*)d_in[17];
    const float* gat_ah = (const float*)d_in[18];
    const float* gat_Wo = (const float*)d_in[19];
    const float* gat_ao = (const float*)d_in[20];
    const float* fuse_w = (const float*)d_in[21];
    const float* trans  = (const float*)d_in[22];

    float* ws = (float*)d_ws;
    float* gat_in = ws;                         // 1,572,864
    float* xw_f   = gat_in + 1572864;
    float* xw_b   = xw_f   + 1572864;
    float* base   = xw_b   + 1572864;

    // big path needs ~104.6 MB; fall back to the serial R6 layout otherwise.
    const bool big = ws_size >= 106000000ull;

    float *h1, *out1, *h2, *f1g, *f2g, *f1o, *f2o, *out2, *feats;
    unsigned long long* packed;
    if (big) {
        h1    = base;                 // 3*H1SZ
        out1  = h1   + 3 * (size_t)H1SZ;
        h2    = out1 + 3 * (size_t)OUT1SZ;
        f1g   = h2   + 3 * (size_t)H2SZ;
        f2g   = f1g  + 3 * (size_t)FGSZ;
        f1o   = f2g  + 3 * (size_t)FGSZ;
        f2o   = f1o  + 3 * (size_t)FOSZ;
        out2  = f2o  + 3 * (size_t)FOSZ;
        feats = out2 + 3 * (size_t)OUT2SZ;
        packed = (unsigned long long*)(feats + OUT2SZ);
    } else {
        h1    = base;                 // H1SZ
        out1  = h1   + (size_t)H1SZ;
        h2    = out1 + (size_t)OUT1SZ;
        f1g   = h2   + (size_t)H2SZ;
        f2g   = f1g  + (size_t)FGSZ;
        f1o   = f2g  + (size_t)FGSZ;
        f2o   = f1o  + (size_t)FOSZ;
        out2  = f2o  + (size_t)FOSZ;  // 3*OUT2SZ (always x3)
        feats = out2 + 3 * (size_t)OUT2SZ;
        packed = (unsigned long long*)(feats + OUT2SZ);
    }

    k_xw<<<dim3(96, 8), 256, 0, stream>>>(batch_char, char_table, w_ih_f, b_f,
                                          w_ih_b, b_b, xw_f, xw_b);
    k_pre<<<PRE_GRID, 256, 0, stream>>>(xw_f, xw_b, w_hh_f, w_hh_b, gat_in,
                                        gaz_list, gaz_table,
                                        graphs[0], graphs[1], graphs[2], packed);
    if (big) {
        // all 3 graphs concurrent: 4 launches, z = k, disjoint buffers
        k_p1<<<dim3(192, 4, 3), 256, 0, stream>>>(gat_in, gat_Wh, gat_ah, 0,
                                                  h1, f1g, f2g, H1SZ, FGSZ);
        k_attn1<<<dim3(BN, 1, 3), 256, 0, stream>>>(packed, h1, f1g, f2g, out1,
                                                    PKSZ, H1SZ, FGSZ, OUT1SZ);
        k_p2<<<dim3(1024, 1, 3), 256, 0, stream>>>(out1, gat_Wo, gat_ao, 0,
                                                   h2, f1o, f2o, OUT1SZ, H2SZ, FOSZ);
        k_attn2<<<dim3(BS, 1, 3), 64, 0, stream>>>(packed, h2, f1o, f2o, out2,
                                                   PKSZ, H2SZ, FOSZ, OUT2SZ);
    } else {
        for (int k = 0; k < 3; ++k) {
            const unsigned long long* pk = packed + (size_t)k * PKSZ;
            k_p1<<<dim3(192, 4, 1), 256, 0, stream>>>(gat_in, gat_Wh, gat_ah, k,
                                                      h1, f1g, f2g, 0, 0);
            k_attn1<<<dim3(BN, 1, 1), 256, 0, stream>>>(pk, h1, f1g, f2g, out1,
                                                        0, 0, 0, 0);
            k_p2<<<dim3(1024, 1, 1), 256, 0, stream>>>(out1, gat_Wo, gat_ao, k,
                                                       h2, f1o, f2o, 0, 0, 0);
            k_attn2<<<dim3(BS, 1, 1), 64, 0, stream>>>(pk, h2, f1o, f2o,
                                                       out2 + (size_t)k * OUT2SZ,
                                                       0, 0, 0, 0);
        }
    }
    k_fuse<<<BS, 64, 0, stream>>>(gat_in, h2h_W, h2h_b, fuse_w, out2, feats);
    k_vit<<<BB, 64, 0, stream>>>(feats, trans, (int*)d_out);
}

// Round 8
// 855.561 us; speedup vs baseline: 1.3361x; 1.0287x over previous
//
#include <hip/hip_runtime.h>
#include <hip/hip_bf16.h>
#include <cstdint>
#include <cstddef>

// Problem constants (match reference)
#define BB 16
#define SS 384
#define GG 384
#define NN 768          // S + G
#define DD 128
#define EC 100
#define TT 21
#define NHEADS 4
#define BN (BB*NN)      // 12288
#define BS (BB*SS)      // 6144

// mega-kernel block layout: [0,32) LSTM, [32,3104) gaz, [3104, 3104+3*BN) pack
#define GAZ_BASE  32
#define PACK_BASE (32 + 3072)
#define PRE_GRID  (PACK_BASE + 3 * BN)

// per-k buffer sizes (floats / u64)
#define H1SZ   3145728
#define OUT1SZ 3145728
#define H2SZ   258048
#define FGSZ   49152
#define FOSZ   12288
#define OUT2SZ 129024
#define PKSZ   ((size_t)BN * 12)

typedef float v2f __attribute__((ext_vector_type(2)));

__device__ __forceinline__ float sigf(float x) { return 1.0f / (1.0f + __expf(-x)); }
__device__ __forceinline__ float tanh_fast(float x) {
    // 1 - 2/(exp(2x)+1); exp overflow -> inf -> 1, underflow -> 0 -> -1
    return 1.0f - 2.0f / (__expf(2.0f * x) + 1.0f);
}
__device__ __forceinline__ float wred_max(float v) {
    #pragma unroll
    for (int o = 32; o > 0; o >>= 1) v = fmaxf(v, __shfl_xor(v, o));
    return v;
}
__device__ __forceinline__ float wred_sum(float v) {
    #pragma unroll
    for (int o = 32; o > 0; o >>= 1) v += __shfl_xor(v, o);
    return v;
}

// ---------------------------------------------------------------------------
// xw = emb @ w_ih^T + b for both directions.  Tiled GEMM with char gather.
// grid (96 row-tiles, 8): blockIdx.y -> dir(2) x gate-tile(4).  64x64 tiles.
// ---------------------------------------------------------------------------
__global__ __launch_bounds__(256) void k_xw(
    const int* __restrict__ batch_char, const float* __restrict__ char_table,
    const float* __restrict__ w_ih_f, const float* __restrict__ b_f,
    const float* __restrict__ w_ih_b, const float* __restrict__ b_b,
    float* __restrict__ xw_f, float* __restrict__ xw_b)
{
    __shared__ float At[EC * 68];   // [e][row]
    __shared__ float Bt[EC * 68];   // [e][gate]
    __shared__ int   chs[64];
    const int tid = threadIdx.x;
    const int rt  = blockIdx.x;             // row tile (64 rows of B*S)
    const int ot  = blockIdx.y;             // dir*4 + gate tile
    const int dir = ot >> 2, gt = ot & 3;
    const float* wih  = dir ? w_ih_b : w_ih_f;
    const float* bias = dir ? b_b    : b_f;
    float*       out  = dir ? xw_b   : xw_f;

    if (tid < 64) chs[tid] = batch_char[rt * 64 + tid];
    __syncthreads();
    for (int idx = tid; idx < 64 * EC; idx += 256) {
        int r = idx / EC, e = idx - r * EC;
        At[e * 68 + r] = char_table[(size_t)chs[r] * EC + e];
        Bt[e * 68 + r] = wih[(size_t)(gt * 64 + r) * EC + e];
    }
    __syncthreads();

    const int ty = tid >> 4, tx = tid & 15;
    const int r0 = ty * 4, c0 = tx * 4;
    float acc[4][4] = {};
    #pragma unroll 4
    for (int e = 0; e < EC; ++e) {
        float4 a = *(const float4*)&At[e * 68 + r0];
        float4 bv = *(const float4*)&Bt[e * 68 + c0];
        float av[4] = {a.x, a.y, a.z, a.w};
        float bb[4] = {bv.x, bv.y, bv.z, bv.w};
        #pragma unroll
        for (int i = 0; i < 4; ++i)
            #pragma unroll
            for (int j = 0; j < 4; ++j) acc[i][j] = fmaf(av[i], bb[j], acc[i][j]);
    }
    #pragma unroll
    for (int i = 0; i < 4; ++i) {
        int row = rt * 64 + r0 + i;
        int gc  = gt * 64 + c0;
        float4 o;
        o.x = acc[i][0] + bias[gc + 0];
        o.y = acc[i][1] + bias[gc + 1];
        o.z = acc[i][2] + bias[gc + 2];
        o.w = acc[i][3] + bias[gc + 3];
        *(float4*)&out[(size_t)row * 256 + gc] = o;
    }
}

// ---------------------------------------------------------------------------
// Mega-kernel: BiLSTM scan (blocks 0..31, the R0 200us version) + gaz gather
// (blocks 32..3103) + adjacency ballot-pack for all 3 graphs (blocks 3104+).
// The gaz/pack work runs on the 224 CUs the 32 LSTM blocks leave idle.
// adj/gaz reads are single-use -> non-temporal, so they don't evict the
// LSTM's xw stream from L2.
// ---------------------------------------------------------------------------
__global__ __launch_bounds__(256) void k_pre(
    const float* __restrict__ xw_f, const float* __restrict__ xw_b,
    const float* __restrict__ w_hh_f, const float* __restrict__ w_hh_b,
    float* __restrict__ gat_in,
    const int* __restrict__ gaz_list, const float* __restrict__ gaz_table,
    const int* __restrict__ adj0, const int* __restrict__ adj1,
    const int* __restrict__ adj2, unsigned long long* __restrict__ packed)
{
    __shared__ float part[2][4][64][4];   // [buf][wave][unit][g4] (LSTM only)
    __shared__ float hbuf[4][64];         // per-wave private copy of h
    const int bid = blockIdx.x;
    const int tid = threadIdx.x;

    if (bid < 32) {
        // ------- BiLSTM scan: R0-verbatim (measured 200.8us) -------
        const int wv = tid >> 6, lane = tid & 63;
        const int b = bid >> 1, dir = bid & 1;
        const float* xw  = (dir ? xw_b : xw_f) + (size_t)b * SS * 256;
        const float* whh = dir ? w_hh_b : w_hh_f;
        v2f w2[4][8];
        #pragma unroll
        for (int g4 = 0; g4 < 4; ++g4) {
            const float* r = whh + (size_t)(g4 * 64 + lane) * 64 + 16 * wv;
            #pragma unroll
            for (int jj = 0; jj < 8; ++jj) w2[g4][jj] = v2f{r[2 * jj], r[2 * jj + 1]};
        }
        hbuf[wv][lane] = 0.f;                 // own-wave copy; in-order LDS
        float c = 0.f;
        int buf = 0;
        const int t0 = dir ? (SS - 1) : 0;
        float x0 = xw[t0 * 256 +   0 + lane];
        float x1 = xw[t0 * 256 +  64 + lane];
        float x2 = xw[t0 * 256 + 128 + lane];
        float x3 = xw[t0 * 256 + 192 + lane];
        const v2f* h2p = (const v2f*)&hbuf[wv][16 * wv];   // 8 v2f chunk
        for (int tt = 0; tt < SS; ++tt) {
            const int t = dir ? (SS - 1 - tt) : tt;
            const int tn = dir ? (t - 1) : (t + 1);
            v2f a0 = v2f{0.f, 0.f}, a1 = v2f{0.f, 0.f}, a2 = v2f{0.f, 0.f}, a3 = v2f{0.f, 0.f};
            #pragma unroll
            for (int jj = 0; jj < 8; ++jj) {
                v2f hv = h2p[jj];
                a0 = __builtin_elementwise_fma(hv, w2[0][jj], a0);
                a1 = __builtin_elementwise_fma(hv, w2[1][jj], a1);
                a2 = __builtin_elementwise_fma(hv, w2[2][jj], a2);
                a3 = __builtin_elementwise_fma(hv, w2[3][jj], a3);
            }
            float4 pw;
            pw.x = a0.x + a0.y; pw.y = a1.x + a1.y;
            pw.z = a2.x + a2.y; pw.w = a3.x + a3.y;
            *(float4*)part[buf][wv][lane] = pw;
            float nx0 = 0.f, nx1 = 0.f, nx2 = 0.f, nx3 = 0.f;
            if (tt + 1 < SS) {
                nx0 = xw[tn * 256 +   0 + lane];
                nx1 = xw[tn * 256 +  64 + lane];
                nx2 = xw[tn * 256 + 128 + lane];
                nx3 = xw[tn * 256 + 192 + lane];
            }
            __syncthreads();
            float4 p0 = *(const float4*)part[buf][0][lane];
            float4 p1 = *(const float4*)part[buf][1][lane];
            float4 p2 = *(const float4*)part[buf][2][lane];
            float4 p3 = *(const float4*)part[buf][3][lane];
            float gi = ((p0.x + p1.x) + (p2.x + p3.x)) + x0;
            float gf = ((p0.y + p1.y) + (p2.y + p3.y)) + x1;
            float gg = ((p0.z + p1.z) + (p2.z + p3.z)) + x2;
            float go = ((p0.w + p1.w) + (p2.w + p3.w)) + x3;
            float nc = sigf(gf) * c + sigf(gi) * tanh_fast(gg);
            float nh = sigf(go) * tanh_fast(nc);
            c = nc;
            hbuf[wv][lane] = nh;              // own-wave copy; read next step
            if (wv == 0) gat_in[((size_t)b * NN + t) * DD + dir * 64 + lane] = nh;
            x0 = nx0; x1 = nx1; x2 = nx2; x3 = nx3;
            buf ^= 1;
        }
    } else if (bid < PACK_BASE) {
        // ------- gaz embedding gather into gat_in rows [S, N) -------
        int idx = (bid - GAZ_BASE) * 256 + tid;        // B*G*128 total
        int d = idx & 127;
        int rest = idx >> 7;
        int g = rest % GG;
        int b = rest / GG;
        int gi = __builtin_nontemporal_load(&gaz_list[b * GG + g]);
        float v = __builtin_nontemporal_load(&gaz_table[(size_t)gi * DD + d]);
        gat_in[((size_t)b * NN + SS + g) * DD + d] = v;
    } else {
        // ------- adjacency ballot-pack, all 3 graphs -------
        const int row = bid - PACK_BASE;               // 0 .. 3*BN-1
        const int k = row / BN, n = row - k * BN;
        const int* adjk = (k == 0) ? adj0 : ((k == 1) ? adj1 : adj2);
        const int wave = tid >> 6, lane = tid & 63;
        #pragma unroll
        for (int it = 0; it < 3; ++it) {
            int j = it * 256 + tid;
            int a = __builtin_nontemporal_load(&adjk[(size_t)n * NN + j]);
            unsigned long long m = __ballot(a > 0);
            if (lane == 0)
                packed[((size_t)k * BN + n) * 12 + it * 4 + wave] = m;
        }
    }
}

// ---------------------------------------------------------------------------
// GAT layer-1 projection: h1 = gat_in @ Wh[k][hd] (+ per-row f1/f2 dots).
// grid (192 row-tiles, 4 heads, Z ks).  Bt staging uses a transposed index
// decode so W reads are coalesced (same data -> bitwise identical).
// ---------------------------------------------------------------------------
__global__ __launch_bounds__(256) void k_p1(
    const float* __restrict__ gat_in, const float* __restrict__ gat_Wh,
    const float* __restrict__ gat_ah, int k0,
    float* __restrict__ h1, float* __restrict__ f1g, float* __restrict__ f2g,
    size_t zh1, size_t zfg)
{
    __shared__ float At[64 * 68];
    __shared__ float Bt[64 * 68];
    __shared__ float sf1[64], sf2[64];
    const int tid = threadIdx.x;
    const int rt = blockIdx.x, hd = blockIdx.y, z = blockIdx.z;
    const int k = k0 + z;
    float* h1p = h1 + (size_t)z * zh1;
    float* f1p = f1g + (size_t)z * zfg;
    float* f2p = f2g + (size_t)z * zfg;
    if (tid < 64) { sf1[tid] = 0.f; sf2[tid] = 0.f; }
    const float* W = gat_Wh + ((size_t)(k * NHEADS + hd)) * DD * 64;
    const int ty = tid >> 4, tx = tid & 15;
    const int r0 = ty * 4, c0 = tx * 4;
    float acc[4][4] = {};
    for (int ph = 0; ph < 2; ++ph) {
        __syncthreads();
        for (int idx = tid; idx < 64 * 64; idx += 256) {
            int r = idx >> 6, e = idx & 63;
            At[e * 68 + r] = gat_in[((size_t)(rt * 64 + r)) * DD + ph * 64 + e];
            int rB = idx & 63, eB = idx >> 6;   // transposed decode: W coalesced
            Bt[eB * 68 + rB] = W[(size_t)(ph * 64 + eB) * 64 + rB];
        }
        __syncthreads();
        #pragma unroll 4
        for (int e = 0; e < 64; ++e) {
            float4 a = *(const float4*)&At[e * 68 + r0];
            float4 bv = *(const float4*)&Bt[e * 68 + c0];
            float av[4] = {a.x, a.y, a.z, a.w};
            float bb[4] = {bv.x, bv.y, bv.z, bv.w};
            #pragma unroll
            for (int i = 0; i < 4; ++i)
                #pragma unroll
                for (int j = 0; j < 4; ++j) acc[i][j] = fmaf(av[i], bb[j], acc[i][j]);
        }
    }
    const float* ah = gat_ah + (size_t)(k * NHEADS + hd) * 128;
    float a1[4], a2[4];
    #pragma unroll
    for (int j = 0; j < 4; ++j) { a1[j] = ah[c0 + j]; a2[j] = ah[64 + c0 + j]; }
    #pragma unroll
    for (int i = 0; i < 4; ++i) {
        int n = rt * 64 + r0 + i;
        float4 o = make_float4(acc[i][0], acc[i][1], acc[i][2], acc[i][3]);
        *(float4*)&h1p[((size_t)n * NHEADS + hd) * 64 + c0] = o;
        float p1 = acc[i][0] * a1[0] + acc[i][1] * a1[1] + acc[i][2] * a1[2] + acc[i][3] * a1[3];
        float p2 = acc[i][0] * a2[0] + acc[i][1] * a2[1] + acc[i][2] * a2[2] + acc[i][3] * a2[3];
        atomicAdd(&sf1[r0 + i], p1);
        atomicAdd(&sf2[r0 + i], p2);
    }
    __syncthreads();
    if (tid < 64) {
        f1p[hd * BN + rt * 64 + tid] = sf1[tid];
        f2p[hd * BN + rt * 64 + tid] = sf2[tid];
    }
}

// ---------------------------------------------------------------------------
// GAT layer-1 attention (sparse).  grid (BN, 1, Z); wave = head.
// XCD b-locality swizzle: xcd = bid&7 (round-robin dispatch) -> each XCD
// handles exactly 2 batches, shrinking its h1 gather working set from
// ~37MB (all b,k) to ~4.7MB (~L2-fit).  Pure bijective index remap ->
// bitwise identical.  out1 stores are non-temporal so the 12.6MB/graph of
// output doesn't evict the gather set.
// ---------------------------------------------------------------------------
__global__ __launch_bounds__(256) void k_attn1(
    const unsigned long long* __restrict__ packed, const float* __restrict__ h1,
    const float* __restrict__ f1g, const float* __restrict__ f2g,
    float* __restrict__ out1,
    size_t zpk, size_t zh1, size_t zfg, size_t zout1)
{
    __shared__ int   nbr[NN];
    __shared__ float ep[NHEADS][NN];
    __shared__ int cntS;
    const int tid = threadIdx.x, wave = tid >> 6, lane = tid & 63;
    const int bid = blockIdx.x, z = blockIdx.z;
    const int xcd = bid & 7;
    const int local = bid >> 3;                 // 0..1535
    const int b = 2 * xcd + ((local >= NN) ? 1 : 0);
    const int i = (local >= NN) ? (local - NN) : local;
    const int n = b * NN + i;
    const unsigned long long* pkp = packed + (size_t)z * zpk;
    const float* h1p = h1 + (size_t)z * zh1;
    const float* f1p = f1g + (size_t)z * zfg;
    const float* f2gp = f2g + (size_t)z * zfg;
    float* out1p = out1 + (size_t)z * zout1;
    if (wave == 0) {
        unsigned long long m = (lane < 12) ? pkp[(size_t)n * 12 + lane] : 0ULL;
        int pc = __popcll(m);
        int inc = pc;
        #pragma unroll
        for (int d = 1; d < 16; d <<= 1) { int t = __shfl_up(inc, d); if (lane >= d) inc += t; }
        int C = __shfl(inc, 11);
        if (lane == 0) cntS = C;
        int off = inc - pc;
        while (m) {
            int bit = __builtin_ctzll(m);
            nbr[off++] = lane * 64 + bit;
            m &= m - 1;
        }
    }
    __syncthreads();
    const int C = cntS;
    const int hd = wave;
    const float f1 = f1p[hd * BN + n];
    const float* f2p = f2gp + hd * BN + b * NN;
    float mx = -3.0e38f;
    for (int t = lane; t < C; t += 64) {
        float e = f1 + f2p[nbr[t]];
        e = (e >= 0.f) ? e : 0.2f * e;
        ep[hd][t] = e;
        mx = fmaxf(mx, e);
    }
    mx = wred_max(mx);
    float sum = 0.f;
    for (int t = lane; t < C; t += 64) {
        float p = __expf(ep[hd][t] - mx);
        ep[hd][t] = p;
        sum += p;
    }
    sum = wred_sum(sum);
    const float* hb = h1p + (size_t)b * NN * (NHEADS * 64) + hd * 64 + lane;
    float ac0 = 0.f, ac1 = 0.f, ac2 = 0.f, ac3 = 0.f;
    int t = 0;
    for (; t + 3 < C; t += 4) {
        int j0 = nbr[t], j1 = nbr[t + 1], j2 = nbr[t + 2], j3 = nbr[t + 3];
        float p0 = ep[hd][t], p1 = ep[hd][t + 1], p2 = ep[hd][t + 2], p3 = ep[hd][t + 3];
        ac0 = fmaf(p0, hb[(size_t)j0 * 256], ac0);
        ac1 = fmaf(p1, hb[(size_t)j1 * 256], ac1);
        ac2 = fmaf(p2, hb[(size_t)j2 * 256], ac2);
        ac3 = fmaf(p3, hb[(size_t)j3 * 256], ac3);
    }
    for (; t < C; ++t) ac0 = fmaf(ep[hd][t], hb[(size_t)nbr[t] * 256], ac0);
    float r = ((ac0 + ac1) + (ac2 + ac3)) / sum;
    r = (r > 0.f) ? r : expm1f(r);
    __builtin_nontemporal_store(r, &out1p[(size_t)n * 256 + hd * 64 + lane]);
}

// ---------------------------------------------------------------------------
// Output-layer projection: h2 = out1 @ Wo[k].  grid (1024, 1, Z).
// ---------------------------------------------------------------------------
__global__ __launch_bounds__(256) void k_p2(
    const float* __restrict__ out1, const float* __restrict__ gat_Wo,
    const float* __restrict__ gat_ao, int k0,
    float* __restrict__ h2, float* __restrict__ f1o, float* __restrict__ f2o,
    size_t zout1, size_t zh2, size_t zfo)
{
    __shared__ float ld[12 * 256];
    __shared__ float lf1[12], lf2[12];
    const int tid = threadIdx.x;
    const int blk = blockIdx.x, z = blockIdx.z;
    const int k = k0 + z;
    const float* out1p = out1 + (size_t)z * zout1;
    float* h2p = h2 + (size_t)z * zh2;
    float* f1op = f1o + (size_t)z * zfo;
    float* f2op = f2o + (size_t)z * zfo;
    if (tid < 12) { lf1[tid] = 0.f; lf2[tid] = 0.f; }
    for (int idx = tid; idx < 12 * 256; idx += 256)
        ld[idx] = out1p[(size_t)blk * 12 * 256 + idx];
    __syncthreads();
    if (tid < 252) {
        const int r = tid / TT, c = tid - r * TT;
        const float* Wo = gat_Wo + (size_t)k * 256 * TT;
        const float4* row4 = (const float4*)&ld[r * 256];
        float acc = 0.f;
        #pragma unroll 8
        for (int q4 = 0; q4 < 64; ++q4) {
            float4 v = row4[q4];
            int q = q4 * 4;
            acc = fmaf(v.x, Wo[(q + 0) * TT + c], acc);
            acc = fmaf(v.y, Wo[(q + 1) * TT + c], acc);
            acc = fmaf(v.z, Wo[(q + 2) * TT + c], acc);
            acc = fmaf(v.w, Wo[(q + 3) * TT + c], acc);
        }
        const int n = blk * 12 + r;
        h2p[(size_t)n * TT + c] = acc;
        const float* ao = gat_ao + k * 2 * TT;
        atomicAdd(&lf1[r], acc * ao[c]);
        atomicAdd(&lf2[r], acc * ao[TT + c]);
    }
    __syncthreads();
    if (tid < 12) {
        f1op[blk * 12 + tid] = lf1[tid];
        f2op[blk * 12 + tid] = lf2[tid];
    }
}

// ---------------------------------------------------------------------------
// Output-layer attention + elu.  grid (BS, 1, Z); one wave per (b, s<S).
// Same XCD b-locality swizzle as k_attn1.
// ---------------------------------------------------------------------------
__global__ __launch_bounds__(64) void k_attn2(
    const unsigned long long* __restrict__ packed,
    const float* __restrict__ h2, const float* __restrict__ f1o,
    const float* __restrict__ f2o, float* __restrict__ out2,
    size_t zpk, size_t zh2, size_t zfo, size_t zout2)
{
    __shared__ int   nbr[NN];
    __shared__ float ep[NN];
    const int lane = threadIdx.x;
    const int bid = blockIdx.x, z = blockIdx.z;
    const int xcd = bid & 7;
    const int local = bid >> 3;                 // 0..767
    const int b = 2 * xcd + ((local >= SS) ? 1 : 0);
    const int s = (local >= SS) ? (local - SS) : local;
    const int blk = b * SS + s;
    const int n = b * NN + s;
    const unsigned long long* pkp = packed + (size_t)z * zpk;
    const float* h2p = h2 + (size_t)z * zh2;
    const float* f1op = f1o + (size_t)z * zfo;
    const float* f2op = f2o + (size_t)z * zfo;
    float* out2k = out2 + (size_t)z * zout2;
    unsigned long long w64 = (lane < 12) ? pkp[(size_t)n * 12 + lane] : 0ULL;
    int pc = __popcll(w64);
    int inc = pc;
    #pragma unroll
    for (int d = 1; d < 16; d <<= 1) {
        int t = __shfl_up(inc, d, 16);
        if ((lane & 15) >= d) inc += t;
    }
    const int C = __shfl(inc, 11);
    int off = inc - pc;
    while (w64) {
        int bit = __builtin_ctzll(w64);
        nbr[off++] = lane * 64 + bit;
        w64 &= w64 - 1;
    }
    __syncthreads();
    const float f1 = f1op[n];
    const float* f2p = f2op + b * NN;
    float mx = -3.0e38f;
    for (int t = lane; t < C; t += 64) {
        int j = nbr[t];
        float e = f1 + f2p[j];
        e = (e >= 0.f) ? e : 0.2f * e;
        ep[t] = e;
        mx = fmaxf(mx, e);
    }
    mx = wred_max(mx);
    float sum = 0.f;
    for (int t = lane; t < C; t += 64) {
        float p = __expf(ep[t] - mx);
        ep[t] = p;
        sum += p;
    }
    sum = wred_sum(sum);
    const float* h2b = h2p + (size_t)b * NN * TT + ((lane < TT) ? lane : 0);
    float ac0 = 0.f, ac1 = 0.f, ac2 = 0.f, ac3 = 0.f;
    int t = 0;
    for (; t + 3 < C; t += 4) {
        int j0 = nbr[t], j1 = nbr[t + 1], j2 = nbr[t + 2], j3 = nbr[t + 3];
        float p0 = ep[t], p1 = ep[t + 1], p2 = ep[t + 2], p3 = ep[t + 3];
        ac0 = fmaf(p0, h2b[(size_t)j0 * TT], ac0);
        ac1 = fmaf(p1, h2b[(size_t)j1 * TT], ac1);
        ac2 = fmaf(p2, h2b[(size_t)j2 * TT], ac2);
        ac3 = fmaf(p3, h2b[(size_t)j3 * TT], ac3);
    }
    for (; t < C; ++t) ac0 = fmaf(ep[t], h2b[(size_t)nbr[t] * TT], ac0);
    if (lane < TT) {
        float r = ((ac0 + ac1) + (ac2 + ac3)) / sum;
        r = (r > 0.f) ? r : expm1f(r);
        out2k[(size_t)blk * TT + lane] = r;
    }
}

// ---------------------------------------------------------------------------
// feats = fuse_w[0]*(lstm_feat@h2h_W^T + b) + sum_k fuse_w[k+1]*out2_k
// ---------------------------------------------------------------------------
__global__ __launch_bounds__(64) void k_fuse(
    const float* __restrict__ gat_in, const float* __restrict__ h2h_W,
    const float* __restrict__ h2h_b, const float* __restrict__ fuse_w,
    const float* __restrict__ out2, float* __restrict__ feats)
{
    __shared__ float row[DD];
    const int lane = threadIdx.x;
    const int blk = blockIdx.x;                 // b*S + s
    const int b = blk / SS, s = blk - b * SS;
    const float* src = gat_in + ((size_t)b * NN + s) * DD;
    row[lane] = src[lane];
    row[lane + 64] = src[lane + 64];
    __syncthreads();
    if (lane < TT) {
        float acc = h2h_b[lane];
        const float4* w4 = (const float4*)&h2h_W[lane * DD];
        const float4* r4 = (const float4*)row;
        #pragma unroll 8
        for (int d4 = 0; d4 < 32; ++d4) {
            float4 w = w4[d4]; float4 v = r4[d4];
            acc = fmaf(w.x, v.x, acc); acc = fmaf(w.y, v.y, acc);
            acc = fmaf(w.z, v.z, acc); acc = fmaf(w.w, v.w, acc);
        }
        size_t o = (size_t)blk * TT + lane;
        feats[o] = fuse_w[0] * acc + fuse_w[1] * out2[o]
                 + fuse_w[2] * out2[(size_t)BS * TT + o]
                 + fuse_w[3] * out2[2 * (size_t)BS * TT + o];
    }
}

// ---------------------------------------------------------------------------
// Viterbi decode.  One wave per batch; part[] in registers, reg backtrack.
// ---------------------------------------------------------------------------
__global__ __launch_bounds__(64) void k_vit(
    const float* __restrict__ feats, const float* __restrict__ trans,
    int* __restrict__ out)
{
    __shared__ unsigned char bp[SS - 1][24];
    const int lane = threadIdx.x;
    const int b = blockIdx.x;
    const int pg = lane / TT;                 // 0,1,2 (lane 63 idle)
    const int c = lane - pg * TT;
    const bool act = (pg < 3);
    const int p0 = pg * 7;
    float tc[7];
    if (act) {
        #pragma unroll
        for (int u = 0; u < 7; ++u) tc[u] = trans[(p0 + u) * TT + c];
    }
    float pr = (lane < TT)
        ? feats[((size_t)b * SS) * TT + lane] + trans[19 * TT + lane]
        : -3.0e38f;
    float nf = (lane < TT) ? feats[((size_t)b * SS + 1) * TT + lane] : 0.f;
    for (int t = 1; t < SS; ++t) {
        float fcur = nf;
        if (t + 1 < SS)
            nf = (lane < TT) ? feats[((size_t)b * SS + t + 1) * TT + lane] : 0.f;
        float pv[7];
        #pragma unroll
        for (int u = 0; u < 7; ++u) pv[u] = __shfl(pr, p0 + u);
        float best = -3.0e38f; int bi = 0;
        if (act) {
            #pragma unroll
            for (int u = 0; u < 7; ++u) {
                float v = pv[u] + tc[u];
                if (v > best) { best = v; bi = p0 + u; }
            }
        }
        float bv1 = __shfl(best, lane + 21);
        int   bi1 = __shfl(bi,   lane + 21);
        float bv2 = __shfl(best, lane + 42);
        int   bi2 = __shfl(bi,   lane + 42);
        if (bv1 > best) { best = bv1; bi = bi1; }
        if (bv2 > best) { best = bv2; bi = bi2; }
        if (lane < TT) {
            bp[t - 1][lane] = (unsigned char)bi;
            pr = best + fcur;
        }
    }
    float fv = (lane < TT) ? pr + trans[lane * TT + 20] : -3.0e38f;
    int fi = (lane < TT) ? lane : 0;
    #pragma unroll
    for (int o = 32; o > 0; o >>= 1) {
        float ov = __shfl_xor(fv, o);
        int oi = __shfl_xor(fi, o);
        if (ov > fv || (ov == fv && oi < fi)) { fv = ov; fi = oi; }
    }
    int curs = __builtin_amdgcn_readfirstlane(fi);
    if (lane == 0) out[b * SS + SS - 1] = curs;
    int u = SS - 2;                           // 382
    int rem = (u + 1) & 15;                   // 15
    for (int i = 0; i < rem; ++i) {
        int tag = bp[u][curs];                // broadcast LDS read
        curs = __builtin_amdgcn_readfirstlane(tag);
        if (lane == 0) out[b * SS + u] = curs;
        --u;
    }
    const int ll = (lane < 24) ? lane : 0;    // lane = tag for chunk loads
    while (u >= 15) {
        const int base = u - 15;
        int v[16];
        #pragma unroll
        for (int i = 0; i < 16; ++i) v[i] = bp[base + i][ll];
        #pragma unroll
        for (int i = 15; i >= 0; --i) {
            curs = __builtin_amdgcn_readlane(v[i], curs);
            if (lane == 0) out[b * SS + base + i] = curs;
        }
        u = base - 1;
    }
}

// ---------------------------------------------------------------------------
extern "C" void kernel_launch(void* const* d_in, const int* in_sizes, int n_in,
                              void* d_out, int out_size, void* d_ws, size_t ws_size,
                              hipStream_t stream) {
    (void)in_sizes; (void)n_in; (void)out_size;
    const int*   batch_char = (const int*)d_in[0];
    const int*   gaz_list   = (const int*)d_in[2];
    const int*   graphs[3]  = {(const int*)d_in[3], (const int*)d_in[4], (const int*)d_in[5]};
    const float* char_table = (const float*)d_in[7];
    const float* gaz_table  = (const float*)d_in[8];
    const float* w_ih_f = (const float*)d_in[9];
    const float* w_hh_f = (const float*)d_in[10];
    const float* b_f    = (const float*)d_in[11];
    const float* w_ih_b = (const float*)d_in[12];
    const float* w_hh_b = (const float*)d_in[13];
    const float* b_b    = (const float*)d_in[14];
    const float* h2h_W  = (const float*)d_in[15];
    const float* h2h_b  = (const float*)d_in[16];
    const float* gat_Wh = (const float*)d_in[17];
    const float* gat_ah = (const float*)d_in[18];
    const float* gat_Wo = (const float*)d_in[19];
    const float* gat_ao = (const float*)d_in[20];
    const float* fuse_w = (const float*)d_in[21];
    const float* trans  = (const float*)d_in[22];

    float* ws = (float*)d_ws;
    float* gat_in = ws;                         // 1,572,864
    float* xw_f   = gat_in + 1572864;
    float* xw_b   = xw_f   + 1572864;
    float* base   = xw_b   + 1572864;

    // big path needs ~104.6 MB; fall back to the serial R6 layout otherwise.
    const bool big = ws_size >= 106000000ull;

    float *h1, *out1, *h2, *f1g, *f2g, *f1o, *f2o, *out2, *feats;
    unsigned long long* packed;
    if (big) {
        h1    = base;                 // 3*H1SZ
        out1  = h1   + 3 * (size_t)H1SZ;
        h2    = out1 + 3 * (size_t)OUT1SZ;
        f1g   = h2   + 3 * (size_t)H2SZ;
        f2g   = f1g  + 3 * (size_t)FGSZ;
        f1o   = f2g  + 3 * (size_t)FGSZ;
        f2o   = f1o  + 3 * (size_t)FOSZ;
        out2  = f2o  + 3 * (size_t)FOSZ;
        feats = out2 + 3 * (size_t)OUT2SZ;
        packed = (unsigned long long*)(feats + OUT2SZ);
    } else {
        h1    = base;                 // H1SZ
        out1  = h1   + (size_t)H1SZ;
        h2    = out1 + (size_t)OUT1SZ;
        f1g   = h2   + (size_t)H2SZ;
        f2g   = f1g  + (size_t)FGSZ;
        f1o   = f2g  + (size_t)FGSZ;
        f2o   = f1o  + (size_t)FOSZ;
        out2  = f2o  + (size_t)FOSZ;  // 3*OUT2SZ (always x3)
        feats = out2 + 3 * (size_t)OUT2SZ;
        packed = (unsigned long long*)(feats + OUT2SZ);
    }

    k_xw<<<dim3(96, 8), 256, 0, stream>>>(batch_char, char_table, w_ih_f, b_f,
                                          w_ih_b, b_b, xw_f, xw_b);
    k_pre<<<PRE_GRID, 256, 0, stream>>>(xw_f, xw_b, w_hh_f, w_hh_b, gat_in,
                                        gaz_list, gaz_table,
                                        graphs[0], graphs[1], graphs[2], packed);
    if (big) {
        // all 3 graphs concurrent: 4 launches, z = k, disjoint buffers
        k_p1<<<dim3(192, 4, 3), 256, 0, stream>>>(gat_in, gat_Wh, gat_ah, 0,
                                                  h1, f1g, f2g, H1SZ, FGSZ);
        k_attn1<<<dim3(BN, 1, 3), 256, 0, stream>>>(packed, h1, f1g, f2g, out1,
                                                    PKSZ, H1SZ, FGSZ, OUT1SZ);
        k_p2<<<dim3(1024, 1, 3), 256, 0, stream>>>(out1, gat_Wo, gat_ao, 0,
                                                   h2, f1o, f2o, OUT1SZ, H2SZ, FOSZ);
        k_attn2<<<dim3(BS, 1, 3), 64, 0, stream>>>(packed, h2, f1o, f2o, out2,
                                                   PKSZ, H2SZ, FOSZ, OUT2SZ);
    } else {
        for (int k = 0; k < 3; ++k) {
            const unsigned long long* pk = packed + (size_t)k * PKSZ;
            k_p1<<<dim3(192, 4, 1), 256, 0, stream>>>(gat_in, gat_Wh, gat_ah, k,
                                                      h1, f1g, f2g, 0, 0);
            k_attn1<<<dim3(BN, 1, 1), 256, 0, stream>>>(pk, h1, f1g, f2g, out1,
                                                        0, 0, 0, 0);
            k_p2<<<dim3(1024, 1, 1), 256, 0, stream>>>(out1, gat_Wo, gat_ao, k,
                                                       h2, f1o, f2o, 0, 0, 0);
            k_attn2<<<dim3(BS, 1, 1), 64, 0, stream>>>(pk, h2, f1o, f2o,
                                                       out2 + (size_t)k * OUT2SZ,
                                                       0, 0, 0, 0);
        }
    }
    k_fuse<<<BS, 64, 0, stream>>>(gat_in, h2h_W, h2h_b, fuse_w, out2, feats);
    k_vit<<<BB, 64, 0, stream>>>(feats, trans, (int*)d_out);
}